// Round 15
// baseline (652.477 us; speedup 1.0000x reference)
//
#include <hip/hip_runtime.h>
#include <math.h>

#define NN 20000
#define EE 640000
#define HD 128
#define NC 160      // scan chunks
#define CS 125      // chunk size: NC*CS == NN

typedef unsigned short ushort_t;
typedef __attribute__((ext_vector_type(8))) short short8v;
typedef __attribute__((ext_vector_type(4))) float f32x4;

#define MFMA16(a,b,c) __builtin_amdgcn_mfma_f32_16x16x32_bf16(a,b,c,0,0,0)

__device__ __forceinline__ float sigf(float x) { return 1.0f / (1.0f + __expf(-x)); }

__device__ __forceinline__ ushort_t f2b(float x) {
    unsigned u = __builtin_bit_cast(unsigned, x);
    unsigned r = (u + 0x7FFFu + ((u >> 16) & 1u)) >> 16;
    return (ushort_t)r;
}
__device__ __forceinline__ float b2f(ushort_t u) {
    unsigned v = ((unsigned)u) << 16;
    return __builtin_bit_cast(float, v);
}
// split fp32 -> hi/lo bf16 pair (x ~= hi + lo, error ~2^-17 rel)
__device__ __forceinline__ void splitf(float v, ushort_t& h, ushort_t& l) {
    h = f2b(v);
    l = f2b(v - b2f(h));
}
__device__ __forceinline__ void cvt8x2(const float* p, short8v& hi, short8v& lo) {
    #pragma unroll
    for (int j = 0; j < 8; ++j) {
        float v = p[j];
        ushort_t h, l; splitf(v, h, l);
        hi[j] = (short)h; lo[j] = (short)l;
    }
}

// ---------------- prefix / scatter for counting sort ----------------
__global__ __launch_bounds__(1024) void prefix_kernel(const int* __restrict__ hist,
                                                      int* __restrict__ baseI)
{
    __shared__ int wsum[16];
    const int tid = threadIdx.x, lane = tid & 63, wid = tid >> 6;
    const int PER = 20;                 // 20*1024 >= NN
    int i0 = tid * PER;
    int s = 0;
    for (int k = 0; k < PER; ++k) { int i = i0 + k; if (i < NN) s += hist[i]; }
    int v = s;
    #pragma unroll
    for (int off = 1; off < 64; off <<= 1) {
        int t = __shfl_up(v, off);
        if (lane >= off) v += t;
    }
    if (lane == 63) wsum[wid] = v;
    __syncthreads();
    if (tid == 0) {
        int acc = 0;
        #pragma unroll
        for (int w = 0; w < 16; ++w) { int t = wsum[w]; wsum[w] = acc; acc += t; }
    }
    __syncthreads();
    int excl = v - s + wsum[wid];
    for (int k = 0; k < PER; ++k) {
        int i = i0 + k;
        if (i < NN) { baseI[i] = excl; excl += hist[i]; }
    }
}

__global__ __launch_bounds__(256) void scatter_kernel(const int* __restrict__ ei,
                                                      const int* __restrict__ baseI,
                                                      int* __restrict__ cursor,
                                                      int* __restrict__ perm)
{
    int i = blockIdx.x * 256 + threadIdx.x;
    if (i < EE) {
        int n = ei[i];
        int p = baseI[n] + atomicAdd(&cursor[n], 1);
        perm[p] = i;
    }
}

// ------- prep (weight conversions) + histogram, fused (independent work, one grid) -------
__global__ __launch_bounds__(256) void prep_hist_kernel(
    const int* __restrict__ ei, int* __restrict__ histI,
    const float* __restrict__ We1, const float* __restrict__ We2,
    const float* __restrict__ Wc1, const float* __restrict__ Wn1,
    const float* __restrict__ Wn2, const float* __restrict__ Wip,
    const float* __restrict__ Wxp, const float* __restrict__ Wdt,
    const float* __restrict__ Wop,
    ushort_t* __restrict__ W12b, ushort_t* __restrict__ We2b,
    ushort_t* __restrict__ Wc1b,
    ushort_t* __restrict__ Wn1hi, ushort_t* __restrict__ Wn1lo,
    ushort_t* __restrict__ Wn2hi, ushort_t* __restrict__ Wn2lo,
    ushort_t* __restrict__ Wiphi, ushort_t* __restrict__ Wiplo,
    ushort_t* __restrict__ Wxp8hi, ushort_t* __restrict__ Wxp8lo,
    ushort_t* __restrict__ Wdt2hi, ushort_t* __restrict__ Wdt2lo,
    ushort_t* __restrict__ Wophi, ushort_t* __restrict__ Woplo)
{
    int i = blockIdx.x * 256 + threadIdx.x;
    if (i < EE) atomicAdd(&histI[ei[i]], 1);
    if (i < 256 * 128) {
        int j = i >> 7, k = i & 127;
        W12b[i] = f2b(We1[(j & 127) * 257 + ((j >> 7) << 7) + k]);
        ushort_t h, l;
        splitf(Wn1[i], h, l); Wn1hi[i] = h; Wn1lo[i] = l;
        splitf(Wip[i], h, l); Wiphi[i] = h; Wiplo[i] = l;
    }
    if (i < 128 * 128) {
        We2b[i] = f2b(We2[i]);
        Wc1b[i] = f2b(Wc1[i]);
        ushort_t h, l;
        splitf(Wn2[i], h, l); Wn2hi[i] = h; Wn2lo[i] = l;
        splitf(Wop[i], h, l); Wophi[i] = h; Woplo[i] = l;
        int j = i >> 7, k = i & 127;
        splitf(Wxp[(8 + j) * 128 + k], h, l); Wxp8hi[i] = h; Wxp8lo[i] = l;
        float s = 0.f;
        #pragma unroll
        for (int r = 0; r < 8; ++r) s = fmaf(Wdt[j * 8 + r], Wxp[r * 128 + k], s);
        splitf(s, h, l); Wdt2hi[i] = h; Wdt2lo[i] = l;
    }
}

// ---------------- node projections: P12 = h @ [W1a|W1b]^T ----------------
__global__ __launch_bounds__(256) void p12_kernel(
    const float* __restrict__ h, const ushort_t* __restrict__ W12b,
    ushort_t* __restrict__ P12b)
{
    const int tid = threadIdx.x;
    const int lane = tid & 63;
    const int wid = tid >> 6;
    const int wm = wid >> 1, wn = wid & 1;
    const int g = lane >> 4, r16 = lane & 15;
    const int rbase = blockIdx.x * 128 + wm * 64;

    f32x4 acc[4][8];
    #pragma unroll
    for (int mt = 0; mt < 4; ++mt)
        #pragma unroll
        for (int nt = 0; nt < 8; ++nt) acc[mt][nt] = (f32x4){0.f, 0.f, 0.f, 0.f};

    for (int c = 0; c < 4; ++c) {
        short8v afr[4], bfr[8];
        #pragma unroll
        for (int mt = 0; mt < 4; ++mt) {
            int row = rbase + mt * 16 + r16;
            if (row > NN - 1) row = NN - 1;
            const float* p = h + (size_t)row * HD + c * 32 + g * 8;
            #pragma unroll
            for (int j = 0; j < 8; ++j) afr[mt][j] = (short)f2b(p[j]);
        }
        #pragma unroll
        for (int nt = 0; nt < 8; ++nt)
            bfr[nt] = *(const short8v*)(W12b + (size_t)(wn * 128 + nt * 16 + r16) * 128 + c * 32 + g * 8);
        #pragma unroll
        for (int mt = 0; mt < 4; ++mt)
            #pragma unroll
            for (int nt = 0; nt < 8; ++nt)
                acc[mt][nt] = MFMA16(afr[mt], bfr[nt], acc[mt][nt]);
    }
    #pragma unroll
    for (int mt = 0; mt < 4; ++mt)
        #pragma unroll
        for (int nt = 0; nt < 8; ++nt)
            #pragma unroll
            for (int r = 0; r < 4; ++r) {
                int row = rbase + mt * 16 + g * 4 + r;
                if (row < NN)
                    P12b[(size_t)row * 256 + wn * 128 + nt * 16 + r16] = f2b(acc[mt][nt][r]);
            }
}

// ------- edge phase (MFMA bf16, 64-edge blocks for occupancy, segment-aggregated sums) ------
__global__ __launch_bounds__(256) void edge_mfma(
    const ushort_t* __restrict__ P12b, const float* __restrict__ coord,
    const int* __restrict__ ei, const int* __restrict__ perm,
    const float* __restrict__ We1, const float* __restrict__ be1,
    const ushort_t* __restrict__ We2b, const float* __restrict__ be2,
    const float* __restrict__ watt, const float* __restrict__ batt,
    const ushort_t* __restrict__ Wc1b, const float* __restrict__ bc1,
    const float* __restrict__ Wc2,
    float* __restrict__ mi, float* __restrict__ ssum)
{
    __shared__ ushort_t ybuf[64 * 128];   // 16KB, swizzled: byte = (row<<8) + ((col*2) ^ ((row&15)<<4))
    __shared__ float cdp[64][3];
    __shared__ float wcols[128], be1s[128], be2s[128], bc1s[128], watts[128], wc2s[128];
    __shared__ float pq[2][64];
    __shared__ int ej0s[64];

    const int tid = threadIdx.x;
    const int ebase = blockIdx.x * 64;
    const int lane = tid & 63;
    const int wid = tid >> 6;
    const int wm = wid >> 1, wn = wid & 1;
    const int g = lane >> 4, r16 = lane & 15;
    const float batt0 = batt[0];

    // ---- early: 4 threads per edge; random P1 gather parked in own ybuf quarter ----
    const int e = tid >> 2, qf = tid & 3;
    const int eg = perm[ebase + e];
    const int n0 = ei[eg];
    const int n1 = ei[EE + eg];
    {
        const ushort_t* p1 = P12b + (size_t)n1 * 256 + qf * 32;
        #pragma unroll
        for (int q = 0; q < 4; ++q) {
            short8v t = *(const short8v*)(p1 + q * 8);
            int off = (e << 8) + ((qf * 64 + q * 16) ^ ((e & 15) << 4));
            *(short8v*)((char*)ybuf + off) = t;     // thread-private slot
        }
    }
    if (qf == 0) ej0s[e] = n0;
    // stage per-col consts (latency overlaps gathers)
    {
        int t = tid & 127;
        if (tid < 128) {
            wcols[t] = We1[t * 257 + 256];
            be1s[t] = be1[t];
            be2s[t] = be2[t];
        } else {
            bc1s[t] = bc1[t];
            watts[t] = watt[t];
            wc2s[t] = Wc2[t];
        }
    }
    // radial + coord-diff
    float rr;
    {
        float d0 = coord[n0 * 3 + 0] - coord[n1 * 3 + 0];
        float d1 = coord[n0 * 3 + 1] - coord[n1 * 3 + 1];
        float d2 = coord[n0 * 3 + 2] - coord[n1 * 3 + 2];
        rr = d0 * d0 + d1 * d1 + d2 * d2;
        if (qf == 0) { cdp[e][0] = d0; cdp[e][1] = d1; cdp[e][2] = d2; }
    }
    __syncthreads();

    // ---- phase A: y1 = relu(P1[e1] + P2[e0] + rad*wcol + be1) -> ybuf (in place) ----
    {
        short8v gb[4];
        const ushort_t* p2 = P12b + (size_t)n0 * 256 + 128 + qf * 32;
        #pragma unroll
        for (int q = 0; q < 4; ++q)
            gb[q] = *(const short8v*)(p2 + q * 8);
        const int colbase = qf * 32;
        #pragma unroll
        for (int q = 0; q < 4; ++q) {
            int off = (e << 8) + ((colbase * 2 + q * 16) ^ ((e & 15) << 4));
            short8v a = *(const short8v*)((const char*)ybuf + off);
            short8v ov;
            #pragma unroll
            for (int jj = 0; jj < 8; ++jj) {
                int col = colbase + q * 8 + jj;
                float v = b2f((ushort_t)a[jj]) + b2f((ushort_t)gb[q][jj]) + rr * wcols[col] + be1s[col];
                ov[jj] = (short)f2b(fmaxf(v, 0.f));
            }
            *(short8v*)((char*)ybuf + off) = ov;
        }
    }
    __syncthreads();

    // ---- layer 2: y1 @ We2^T  (wave tile 32 rows x 64 cols; weights loaded inline) ----
    f32x4 acc[2][4];
    #pragma unroll
    for (int mt = 0; mt < 2; ++mt)
        #pragma unroll
        for (int nt = 0; nt < 4; ++nt) acc[mt][nt] = (f32x4){0.f, 0.f, 0.f, 0.f};
    #pragma unroll
    for (int c = 0; c < 4; ++c) {
        short8v afr[2], bfr[4];
        #pragma unroll
        for (int mt = 0; mt < 2; ++mt) {
            int row = wm * 32 + mt * 16 + r16;
            afr[mt] = *(const short8v*)((const char*)ybuf + (row << 8) + ((c * 64 + g * 16) ^ (r16 << 4)));
        }
        #pragma unroll
        for (int nt = 0; nt < 4; ++nt)
            bfr[nt] = *(const short8v*)(We2b + (size_t)(wn * 64 + nt * 16 + r16) * 128 + c * 32 + g * 8);
        #pragma unroll
        for (int mt = 0; mt < 2; ++mt)
            #pragma unroll
            for (int nt = 0; nt < 4; ++nt)
                acc[mt][nt] = MFMA16(afr[mt], bfr[nt], acc[mt][nt]);
    }

    // epilogue 2: mij = relu(+be2); att = sigmoid(mij.watt + batt); ef = mij*att -> ybuf
    {
        float p[2][4];
        #pragma unroll
        for (int mt = 0; mt < 2; ++mt)
            #pragma unroll
            for (int r = 0; r < 4; ++r) p[mt][r] = 0.f;
        #pragma unroll
        for (int mt = 0; mt < 2; ++mt)
            #pragma unroll
            for (int nt = 0; nt < 4; ++nt)
                #pragma unroll
                for (int r = 0; r < 4; ++r) {
                    int col = wn * 64 + nt * 16 + r16;
                    float v = fmaxf(acc[mt][nt][r] + be2s[col], 0.f);
                    acc[mt][nt][r] = v;
                    p[mt][r] += v * watts[col];
                }
        #pragma unroll
        for (int off = 1; off < 16; off <<= 1)
            #pragma unroll
            for (int mt = 0; mt < 2; ++mt)
                #pragma unroll
                for (int r = 0; r < 4; ++r) p[mt][r] += __shfl_xor(p[mt][r], off);
        if (r16 == 0) {
            #pragma unroll
            for (int mt = 0; mt < 2; ++mt)
                #pragma unroll
                for (int r = 0; r < 4; ++r)
                    pq[wn][wm * 32 + mt * 16 + g * 4 + r] = p[mt][r];
        }
        __syncthreads();
        float att[2][4];
        #pragma unroll
        for (int mt = 0; mt < 2; ++mt)
            #pragma unroll
            for (int r = 0; r < 4; ++r) {
                int row = wm * 32 + mt * 16 + g * 4 + r;
                att[mt][r] = sigf(pq[0][row] + pq[1][row] + batt0);
            }
        __syncthreads();   // layer-2 ybuf reads + pq reads done -> safe to overwrite ybuf
        #pragma unroll
        for (int mt = 0; mt < 2; ++mt)
            #pragma unroll
            for (int nt = 0; nt < 4; ++nt)
                #pragma unroll
                for (int r = 0; r < 4; ++r) {
                    int row = wm * 32 + mt * 16 + g * 4 + r;
                    int col = wn * 64 + nt * 16 + r16;
                    int off = (row << 8) + (((col << 1)) ^ ((row & 15) << 4));
                    *(ushort_t*)((char*)ybuf + off) = f2b(acc[mt][nt][r] * att[mt][r]);
                }
    }
    __syncthreads();   // ef visible to all

    // ---- segment-sum ef over sorted e0 runs -> mi (col-per-thread, 32-row halves) ----
    {
        const int col = tid & 127, half = tid >> 7;
        const int r0 = half * 32, r1 = r0 + 32;
        float sacc = 0.f; int cur = ej0s[r0];
        for (int r = r0; r < r1; ++r) {
            int node = ej0s[r];
            if (node != cur) {
                atomicAdd(&mi[(size_t)cur * HD + col], sacc);
                sacc = 0.f; cur = node;
            }
            int off = (r << 8) + (((col << 1)) ^ ((r & 15) << 4));
            sacc += b2f(*(const ushort_t*)((const char*)ybuf + off));
        }
        atomicAdd(&mi[(size_t)cur * HD + col], sacc);
    }

    // ---- layer 3: ef @ Wc1^T, dot Wc2 (weights inline) ----
    #pragma unroll
    for (int mt = 0; mt < 2; ++mt)
        #pragma unroll
        for (int nt = 0; nt < 4; ++nt) acc[mt][nt] = (f32x4){0.f, 0.f, 0.f, 0.f};
    #pragma unroll
    for (int c = 0; c < 4; ++c) {
        short8v afr[2], bfr[4];
        #pragma unroll
        for (int mt = 0; mt < 2; ++mt) {
            int row = wm * 32 + mt * 16 + r16;
            afr[mt] = *(const short8v*)((const char*)ybuf + (row << 8) + ((c * 64 + g * 16) ^ (r16 << 4)));
        }
        #pragma unroll
        for (int nt = 0; nt < 4; ++nt)
            bfr[nt] = *(const short8v*)(Wc1b + (size_t)(wn * 64 + nt * 16 + r16) * 128 + c * 32 + g * 8);
        #pragma unroll
        for (int mt = 0; mt < 2; ++mt)
            #pragma unroll
            for (int nt = 0; nt < 4; ++nt)
                acc[mt][nt] = MFMA16(afr[mt], bfr[nt], acc[mt][nt]);
    }
    {
        float q[2][4];
        #pragma unroll
        for (int mt = 0; mt < 2; ++mt)
            #pragma unroll
            for (int r = 0; r < 4; ++r) q[mt][r] = 0.f;
        #pragma unroll
        for (int mt = 0; mt < 2; ++mt)
            #pragma unroll
            for (int nt = 0; nt < 4; ++nt)
                #pragma unroll
                for (int r = 0; r < 4; ++r) {
                    int col = wn * 64 + nt * 16 + r16;
                    float v = fmaxf(acc[mt][nt][r] + bc1s[col], 0.f);
                    q[mt][r] += v * wc2s[col];
                }
        #pragma unroll
        for (int off = 1; off < 16; off <<= 1)
            #pragma unroll
            for (int mt = 0; mt < 2; ++mt)
                #pragma unroll
                for (int r = 0; r < 4; ++r) q[mt][r] += __shfl_xor(q[mt][r], off);
        if (r16 == 0) {
            #pragma unroll
            for (int mt = 0; mt < 2; ++mt)
                #pragma unroll
                for (int r = 0; r < 4; ++r)
                    pq[wn][wm * 32 + mt * 16 + g * 4 + r] = q[mt][r];
        }
        __syncthreads();
        // coord segment sums: 24 lanes, 8 rows each
        if (tid < 24) {
            int c = tid % 3, seg = tid / 3;
            int r0 = seg * 8, r1 = r0 + 8;
            float sacc = 0.f; int cur = ej0s[r0];
            for (int r = r0; r < r1; ++r) {
                int node = ej0s[r];
                if (node != cur) {
                    atomicAdd(&ssum[cur * 3 + c], sacc);
                    sacc = 0.f; cur = node;
                }
                float tv = pq[0][r] + pq[1][r];
                float tr = cdp[r][c] * tv;
                tr = fminf(fmaxf(tr, -100.f), 100.f);
                sacc += tr;
            }
            atomicAdd(&ssum[cur * 3 + c], sacc);
        }
    }
}

// -- node MLP + LN + clip (split MFMA); fused in_proj (u,z) + coord update; no hn roundtrip --
__global__ __launch_bounds__(256) void node_mfma(
    const float* __restrict__ mi, const float* __restrict__ h,
    const ushort_t* __restrict__ Wn1hi, const ushort_t* __restrict__ Wn1lo,
    const float* __restrict__ bn1,
    const ushort_t* __restrict__ Wn2hi, const ushort_t* __restrict__ Wn2lo,
    const float* __restrict__ bn2,
    const float* __restrict__ lng, const float* __restrict__ lnb,
    const ushort_t* __restrict__ Wiphi, const ushort_t* __restrict__ Wiplo,
    ushort_t* __restrict__ ub, float* __restrict__ zs,
    const float* __restrict__ coord, const float* __restrict__ ssum,
    const int* __restrict__ histI, float* __restrict__ coordout)
{
    __shared__ ushort_t yhi[128 * 128];
    __shared__ ushort_t ylo[128 * 128];
    __shared__ float bn1s[128], bn2s[128], lngs[128], lnbs[128];

    const int tid = threadIdx.x;
    const int nbase = blockIdx.x * 128;
    const int lane = tid & 63;
    const int wid = tid >> 6;
    const int wm = wid >> 1, wn = wid & 1;
    const int g = lane >> 4, r16 = lane & 15;

    if (tid < 128) { bn1s[tid] = bn1[tid]; bn2s[tid] = bn2[tid]; lngs[tid] = lng[tid]; lnbs[tid] = lnb[tid]; }
    __syncthreads();

    // layer 1: [mi | h] @ Wn1^T, K=256, split A and B
    f32x4 acc[4][4];
    #pragma unroll
    for (int mt = 0; mt < 4; ++mt)
        #pragma unroll
        for (int nt = 0; nt < 4; ++nt) acc[mt][nt] = (f32x4){0.f, 0.f, 0.f, 0.f};
    for (int c = 0; c < 8; ++c) {
        short8v ahi[4], alo[4], bhi[4], blo[4];
        #pragma unroll
        for (int mt = 0; mt < 4; ++mt) {
            int row = nbase + wm * 64 + mt * 16 + r16;
            if (row > NN - 1) row = NN - 1;
            const float* src = (c < 4) ? (mi + (size_t)row * HD + c * 32 + g * 8)
                                       : (h + (size_t)row * HD + (c - 4) * 32 + g * 8);
            cvt8x2(src, ahi[mt], alo[mt]);
        }
        #pragma unroll
        for (int nt = 0; nt < 4; ++nt) {
            size_t wo = (size_t)(wn * 64 + nt * 16 + r16) * 256 + c * 32 + g * 8;
            bhi[nt] = *(const short8v*)(Wn1hi + wo);
            blo[nt] = *(const short8v*)(Wn1lo + wo);
        }
        #pragma unroll
        for (int mt = 0; mt < 4; ++mt)
            #pragma unroll
            for (int nt = 0; nt < 4; ++nt) {
                acc[mt][nt] = MFMA16(ahi[mt], bhi[nt], acc[mt][nt]);
                acc[mt][nt] = MFMA16(ahi[mt], blo[nt], acc[mt][nt]);
                acc[mt][nt] = MFMA16(alo[mt], bhi[nt], acc[mt][nt]);
            }
    }
    // relu(+bn1) -> hi/lo LDS pair
    #pragma unroll
    for (int mt = 0; mt < 4; ++mt)
        #pragma unroll
        for (int nt = 0; nt < 4; ++nt)
            #pragma unroll
            for (int r = 0; r < 4; ++r) {
                int row = wm * 64 + mt * 16 + g * 4 + r;
                int col = wn * 64 + nt * 16 + r16;
                int off = (row << 8) + (((col << 1)) ^ ((row & 15) << 4));
                float v = fmaxf(acc[mt][nt][r] + bn1s[col], 0.f);
                ushort_t hh, ll; splitf(v, hh, ll);
                *(ushort_t*)((char*)yhi + off) = hh;
                *(ushort_t*)((char*)ylo + off) = ll;
            }
    __syncthreads();

    // layer 2: y1 @ Wn2^T, split A and B
    #pragma unroll
    for (int mt = 0; mt < 4; ++mt)
        #pragma unroll
        for (int nt = 0; nt < 4; ++nt) acc[mt][nt] = (f32x4){0.f, 0.f, 0.f, 0.f};
    #pragma unroll
    for (int c = 0; c < 4; ++c) {
        short8v ahi[4], alo[4], bhi[4], blo[4];
        #pragma unroll
        for (int mt = 0; mt < 4; ++mt) {
            int row = wm * 64 + mt * 16 + r16;
            int off = (row << 8) + ((c * 64 + g * 16) ^ (r16 << 4));
            ahi[mt] = *(const short8v*)((const char*)yhi + off);
            alo[mt] = *(const short8v*)((const char*)ylo + off);
        }
        #pragma unroll
        for (int nt = 0; nt < 4; ++nt) {
            size_t wo = (size_t)(wn * 64 + nt * 16 + r16) * 128 + c * 32 + g * 8;
            bhi[nt] = *(const short8v*)(Wn2hi + wo);
            blo[nt] = *(const short8v*)(Wn2lo + wo);
        }
        #pragma unroll
        for (int mt = 0; mt < 4; ++mt)
            #pragma unroll
            for (int nt = 0; nt < 4; ++nt) {
                acc[mt][nt] = MFMA16(ahi[mt], bhi[nt], acc[mt][nt]);
                acc[mt][nt] = MFMA16(ahi[mt], blo[nt], acc[mt][nt]);
                acc[mt][nt] = MFMA16(alo[mt], bhi[nt], acc[mt][nt]);
            }
    }
    __syncthreads();   // all layer-2 reads done -> safe to overwrite
    #pragma unroll
    for (int mt = 0; mt < 4; ++mt)
        #pragma unroll
        for (int nt = 0; nt < 4; ++nt)
            #pragma unroll
            for (int r = 0; r < 4; ++r) {
                int row = wm * 64 + mt * 16 + g * 4 + r;
                int col = wn * 64 + nt * 16 + r16;
                int off = (row << 8) + (((col << 1)) ^ ((row & 15) << 4));
                float v = acc[mt][nt][r] + bn2s[col];
                ushort_t hh, ll; splitf(v, hh, ll);
                *(ushort_t*)((char*)yhi + off) = hh;
                *(ushort_t*)((char*)ylo + off) = ll;
            }
    __syncthreads();

    // layernorm + clip; write hn (hi/lo split) back IN PLACE (thread-private slots)
    {
        const int row = tid >> 1, hf = tid & 1;
        float s1 = 0.f, s2 = 0.f;
        float vals[64];
        #pragma unroll
        for (int q = 0; q < 8; ++q) {
            int c8 = hf * 8 + q;
            int off = (row << 8) + ((c8 * 16) ^ ((row & 15) << 4));
            short8v vh = *(const short8v*)((const char*)yhi + off);
            short8v vl = *(const short8v*)((const char*)ylo + off);
            #pragma unroll
            for (int j = 0; j < 8; ++j) {
                float v = b2f((ushort_t)vh[j]) + b2f((ushort_t)vl[j]);
                vals[q * 8 + j] = v;
                s1 += v; s2 += v * v;
            }
        }
        s1 += __shfl_xor(s1, 1);
        s2 += __shfl_xor(s2, 1);
        float mu = s1 * (1.f / HD);
        float var = s2 * (1.f / HD) - mu * mu;
        float rs = rsqrtf(fmaxf(var, 0.f) + 1e-5f);
        #pragma unroll
        for (int q = 0; q < 8; ++q) {
            int c8 = hf * 8 + q;
            short8v oh, ol;
            #pragma unroll
            for (int j = 0; j < 8; ++j) {
                int col = c8 * 8 + j;
                float v = (vals[q * 8 + j] - mu) * rs * lngs[col] + lnbs[col];
                v = fminf(fmaxf(v, -10.f), 10.f);
                ushort_t hh, ll; splitf(v, hh, ll);
                oh[j] = (short)hh; ol[j] = (short)ll;
            }
            int off = (row << 8) + ((c8 * 16) ^ ((row & 15) << 4));
            *(short8v*)((char*)yhi + off) = oh;
            *(short8v*)((char*)ylo + off) = ol;
        }
    }

    // fused coord update (independent; overlaps with barrier)
    {
        int base3 = nbase * 3;
        for (int k = tid; k < 384; k += 256) {
            int idx = base3 + k;
            if (idx < NN * 3) {
                int n = idx / 3;
                coordout[idx] = coord[idx] + ssum[idx] / fmaxf((float)histI[n], 1.f);
            }
        }
    }
    __syncthreads();   // hn (hi/lo) visible to all

    // ---- fused in_proj: xz = hn @ Wip^T (256 cols, 2 passes of 64 cols per wave) ----
    #pragma unroll
    for (int jh = 0; jh < 2; ++jh) {
        #pragma unroll
        for (int mt = 0; mt < 4; ++mt)
            #pragma unroll
            for (int nt = 0; nt < 4; ++nt) acc[mt][nt] = (f32x4){0.f, 0.f, 0.f, 0.f};
        #pragma unroll
        for (int c = 0; c < 4; ++c) {
            short8v ahi[4], alo[4], bhi[4], blo[4];
            #pragma unroll
            for (int mt = 0; mt < 4; ++mt) {
                int row = wm * 64 + mt * 16 + r16;
                int off = (row << 8) + ((c * 64 + g * 16) ^ (r16 << 4));
                ahi[mt] = *(const short8v*)((const char*)yhi + off);
                alo[mt] = *(const short8v*)((const char*)ylo + off);
            }
            #pragma unroll
            for (int nt = 0; nt < 4; ++nt) {
                int j = wn * 128 + jh * 64 + nt * 16 + r16;
                size_t wo = (size_t)j * 128 + c * 32 + g * 8;
                bhi[nt] = *(const short8v*)(Wiphi + wo);
                blo[nt] = *(const short8v*)(Wiplo + wo);
            }
            #pragma unroll
            for (int mt = 0; mt < 4; ++mt)
                #pragma unroll
                for (int nt = 0; nt < 4; ++nt) {
                    acc[mt][nt] = MFMA16(ahi[mt], bhi[nt], acc[mt][nt]);
                    acc[mt][nt] = MFMA16(ahi[mt], blo[nt], acc[mt][nt]);
                    acc[mt][nt] = MFMA16(alo[mt], bhi[nt], acc[mt][nt]);
                }
        }
        #pragma unroll
        for (int mt = 0; mt < 4; ++mt)
            #pragma unroll
            for (int nt = 0; nt < 4; ++nt)
                #pragma unroll
                for (int r = 0; r < 4; ++r) {
                    int row = nbase + wm * 64 + mt * 16 + g * 4 + r;
                    if (row >= NN) continue;
                    int j = wn * 128 + jh * 64 + nt * 16 + r16;
                    float v = acc[mt][nt][r];
                    if (j < HD) ub[(size_t)row * HD + j] = f2b(v);
                    else        zs[(size_t)row * HD + (j - HD)] = v * sigf(v);
                }
    }
}

// ---- fused conv+silu -> uc; B|C = uc@Wxp8^T; dt = softplus(uc@Wdt2^T+bdt)  (split MFMA) ----
__global__ __launch_bounds__(256) void convdt_mfma(
    const ushort_t* __restrict__ ub, const float* __restrict__ cw,
    const float* __restrict__ cb,
    const ushort_t* __restrict__ Wxp8hi, const ushort_t* __restrict__ Wxp8lo,
    const ushort_t* __restrict__ Wdt2hi, const ushort_t* __restrict__ Wdt2lo,
    const float* __restrict__ bdt,
    float* __restrict__ uc, float* __restrict__ Bm, float* __restrict__ Cm,
    float* __restrict__ dt)
{
    __shared__ ushort_t yhi[128 * 128];
    __shared__ ushort_t ylo[128 * 128];
    __shared__ float cws[128][4], cbs[128], bdts[128];

    const int tid = threadIdx.x;
    const int nbase = blockIdx.x * 128;
    const int lane = tid & 63;
    const int wid = tid >> 6;
    const int wm = wid >> 1, wn = wid & 1;
    const int g = lane >> 4, r16 = lane & 15;

    if (tid < 128) {
        cbs[tid] = cb[tid]; bdts[tid] = bdt[tid];
        #pragma unroll
        for (int k = 0; k < 4; ++k) cws[tid][k] = cw[tid * 4 + k];
    }
    __syncthreads();

    // phase 1: causal depthwise conv + silu -> uc (fp32 global) + hi/lo LDS pair
    for (int it = tid; it < 128 * 16; it += 256) {
        int r = it >> 4, cg = it & 15;
        int t = nbase + r;
        int colb = cg * 8;
        float a[8];
        #pragma unroll
        for (int j = 0; j < 8; ++j) a[j] = cbs[colb + j];
        #pragma unroll
        for (int k = 0; k < 4; ++k) {
            int tt = t - 3 + k;
            if (tt >= 0 && tt < NN) {
                short8v uv = *(const short8v*)(ub + (size_t)tt * HD + colb);
                #pragma unroll
                for (int j = 0; j < 8; ++j) a[j] = fmaf(b2f((ushort_t)uv[j]), cws[colb + j][k], a[j]);
            }
        }
        short8v oh, ol;
        f32x4 u0, u1;
        #pragma unroll
        for (int j = 0; j < 8; ++j) {
            float s = (t < NN) ? a[j] * sigf(a[j]) : 0.f;
            ushort_t hh, ll; splitf(s, hh, ll);
            oh[j] = (short)hh; ol[j] = (short)ll;
            if (j < 4) u0[j] = s; else u1[j - 4] = s;
        }
        int off = (r << 8) + ((cg * 16) ^ ((r & 15) << 4));
        *(short8v*)((char*)yhi + off) = oh;
        *(short8v*)((char*)ylo + off) = ol;
        if (t < NN) {
            *(f32x4*)(uc + (size_t)t * HD + colb) = u0;
            *(f32x4*)(uc + (size_t)t * HD + colb + 4) = u1;
        }
    }
    __syncthreads();

    // phase 2: B|C = uc @ Wxp[8:136]^T  (128 cols), split
    f32x4 acc[4][4];
    #pragma unroll
    for (int mt = 0; mt < 4; ++mt)
        #pragma unroll
        for (int nt = 0; nt < 4; ++nt) acc[mt][nt] = (f32x4){0.f, 0.f, 0.f, 0.f};
    #pragma unroll
    for (int c = 0; c < 4; ++c) {
        short8v ahi[4], alo[4], bhi[4], blo[4];
        #pragma unroll
        for (int mt = 0; mt < 4; ++mt) {
            int row = wm * 64 + mt * 16 + r16;
            int off = (row << 8) + ((c * 64 + g * 16) ^ (r16 << 4));
            ahi[mt] = *(const short8v*)((const char*)yhi + off);
            alo[mt] = *(const short8v*)((const char*)ylo + off);
        }
        #pragma unroll
        for (int nt = 0; nt < 4; ++nt) {
            size_t wo = (size_t)(wn * 64 + nt * 16 + r16) * 128 + c * 32 + g * 8;
            bhi[nt] = *(const short8v*)(Wxp8hi + wo);
            blo[nt] = *(const short8v*)(Wxp8lo + wo);
        }
        #pragma unroll
        for (int mt = 0; mt < 4; ++mt)
            #pragma unroll
            for (int nt = 0; nt < 4; ++nt) {
                acc[mt][nt] = MFMA16(ahi[mt], bhi[nt], acc[mt][nt]);
                acc[mt][nt] = MFMA16(ahi[mt], blo[nt], acc[mt][nt]);
                acc[mt][nt] = MFMA16(alo[mt], bhi[nt], acc[mt][nt]);
            }
    }
    #pragma unroll
    for (int mt = 0; mt < 4; ++mt)
        #pragma unroll
        for (int nt = 0; nt < 4; ++nt)
            #pragma unroll
            for (int r = 0; r < 4; ++r) {
                int row = nbase + wm * 64 + mt * 16 + g * 4 + r;
                if (row >= NN) continue;
                int j = wn * 64 + nt * 16 + r16;
                float v = acc[mt][nt][r];
                if (j < 64) Bm[(size_t)row * 64 + j] = v;
                else        Cm[(size_t)row * 64 + (j - 64)] = v;
            }

    // phase 3: dt = softplus(uc @ Wdt2^T + bdt), split
    #pragma unroll
    for (int mt = 0; mt < 4; ++mt)
        #pragma unroll
        for (int nt = 0; nt < 4; ++nt) acc[mt][nt] = (f32x4){0.f, 0.f, 0.f, 0.f};
    #pragma unroll
    for (int c = 0; c < 4; ++c) {
        short8v ahi[4], alo[4], bhi[4], blo[4];
        #pragma unroll
        for (int mt = 0; mt < 4; ++mt) {
            int row = wm * 64 + mt * 16 + r16;
            int off = (row << 8) + ((c * 64 + g * 16) ^ (r16 << 4));
            ahi[mt] = *(const short8v*)((const char*)yhi + off);
            alo[mt] = *(const short8v*)((const char*)ylo + off);
        }
        #pragma unroll
        for (int nt = 0; nt < 4; ++nt) {
            size_t wo = (size_t)(wn * 64 + nt * 16 + r16) * 128 + c * 32 + g * 8;
            bhi[nt] = *(const short8v*)(Wdt2hi + wo);
            blo[nt] = *(const short8v*)(Wdt2lo + wo);
        }
        #pragma unroll
        for (int mt = 0; mt < 4; ++mt)
            #pragma unroll
            for (int nt = 0; nt < 4; ++nt) {
                acc[mt][nt] = MFMA16(ahi[mt], bhi[nt], acc[mt][nt]);
                acc[mt][nt] = MFMA16(ahi[mt], blo[nt], acc[mt][nt]);
                acc[mt][nt] = MFMA16(alo[mt], bhi[nt], acc[mt][nt]);
            }
    }
    #pragma unroll
    for (int mt = 0; mt < 4; ++mt)
        #pragma unroll
        for (int nt = 0; nt < 4; ++nt)
            #pragma unroll
            for (int r = 0; r < 4; ++r) {
                int row = nbase + wm * 64 + mt * 16 + g * 4 + r;
                if (row >= NN) continue;
                int j = wn * 64 + nt * 16 + r16;
                float a = acc[mt][nt][r] + bdts[j];
                float sp = (a > 20.f) ? a : log1pf(__expf(a));
                dt[(size_t)row * HD + j] = sp;
            }
}

// ---------------- chunked SSM scan (2 d-states per thread throughout) ----------------
__global__ __launch_bounds__(256) void scan1_kernel(
    const float* __restrict__ dt, const float* __restrict__ uc,
    const float* __restrict__ Bm, const float* __restrict__ Alog,
    float* __restrict__ cP, float* __restrict__ cS)
{
    int g = blockIdx.x * 256 + threadIdx.x;   // NC*4096 threads
    int c = g >> 12;
    int r = g & 4095;
    int hh = r >> 5;
    int dp = (r & 31) * 2;
    float A0 = -__expf(Alog[hh * 64 + dp]);
    float A1 = -__expf(Alog[hh * 64 + dp + 1]);
    float P0 = 1.f, S0 = 0.f, P1 = 1.f, S1 = 0.f;
    int t0 = c * CS;
    for (int t = t0; t < t0 + CS; ++t) {
        float dtv = dt[t * HD + hh];
        float uv = uc[t * HD + hh];
        float du = dtv * uv;
        float2 bv = *(const float2*)(Bm + (size_t)t * 64 + dp);
        float a0 = __expf(dtv * A0);
        float a1 = __expf(dtv * A1);
        P0 *= a0; P1 *= a1;
        S0 = fmaf(a0, S0, du * bv.x);
        S1 = fmaf(a1, S1, du * bv.y);
    }
    *(float2*)(cP + (size_t)c * 8192 + hh * 64 + dp) = make_float2(P0, P1);
    *(float2*)(cS + (size_t)c * 8192 + hh * 64 + dp) = make_float2(S0, S1);
}

__global__ __launch_bounds__(256) void scan2_kernel(
    const float* __restrict__ cP, const float* __restrict__ cS, float* __restrict__ cI)
{
    int g = blockIdx.x * 256 + threadIdx.x;
    float S = 0.f;
    for (int c = 0; c < NC; ++c) {
        cI[c * 8192 + g] = S;
        S = fmaf(cP[c * 8192 + g], S, cS[c * 8192 + g]);
    }
}

// 2 d-states per thread: 32 lanes per (c,hh); 5-level shfl reduce
__global__ __launch_bounds__(256) void scan3_kernel(
    const float* __restrict__ dt, const float* __restrict__ uc,
    const float* __restrict__ Bm, const float* __restrict__ Cm,
    const float* __restrict__ Alog, const float* __restrict__ Dskip,
    const float* __restrict__ cI, float* __restrict__ y)
{
    int g = blockIdx.x * 256 + threadIdx.x;   // NC*4096 threads
    int c = g >> 12;
    int r = g & 4095;
    int hh = r >> 5;
    int dp = (r & 31) * 2;
    float A0 = -__expf(Alog[hh * 64 + dp]);
    float A1 = -__expf(Alog[hh * 64 + dp + 1]);
    float s0 = cI[c * 8192 + hh * 64 + dp];
    float s1 = cI[c * 8192 + hh * 64 + dp + 1];
    float Dh = Dskip[hh];
    int t0 = c * CS;
    const int lane31 = threadIdx.x & 31;
    for (int t = t0; t < t0 + CS; ++t) {
        float dtv = dt[t * HD + hh];
        float uv = uc[t * HD + hh];
        float du = dtv * uv;
        float2 bv = *(const float2*)(Bm + (size_t)t * 64 + dp);
        float2 cv = *(const float2*)(Cm + (size_t)t * 64 + dp);
        s0 = fmaf(__expf(dtv * A0), s0, du * bv.x);
        s1 = fmaf(__expf(dtv * A1), s1, du * bv.y);
        float yp = fmaf(s0, cv.x, s1 * cv.y);
        #pragma unroll
        for (int off = 1; off < 32; off <<= 1) yp += __shfl_xor(yp, off);
        if (lane31 == 0) y[t * HD + hh] = yp + Dh * uv;
    }
}

// ---------------- out_proj (split MFMA, ~fp32): (y*silu(z)) @ Wop^T ----------------
__global__ __launch_bounds__(256) void out_mfma(
    const float* __restrict__ y, const float* __restrict__ zs,
    const ushort_t* __restrict__ Wophi, const ushort_t* __restrict__ Woplo,
    float* __restrict__ outp)
{
    const int tid = threadIdx.x;
    const int lane = tid & 63;
    const int wid = tid >> 6;
    const int wm = wid >> 1, wn = wid & 1;
    const int g = lane >> 4, r16 = lane & 15;
    const int nbase = blockIdx.x * 128;

    f32x4 acc[4][4];
    #pragma unroll
    for (int mt = 0; mt < 4; ++mt)
        #pragma unroll
        for (int nt = 0; nt < 4; ++nt) acc[mt][nt] = (f32x4){0.f, 0.f, 0.f, 0.f};

    for (int c = 0; c < 4; ++c) {
        short8v ahi[4], alo[4], bhi[4], blo[4];
        #pragma unroll
        for (int mt = 0; mt < 4; ++mt) {
            int row = nbase + wm * 64 + mt * 16 + r16;
            if (row > NN - 1) row = NN - 1;
            const float* yp = y + (size_t)row * HD + c * 32 + g * 8;
            const float* zp = zs + (size_t)row * HD + c * 32 + g * 8;
            #pragma unroll
            for (int j = 0; j < 8; ++j) {
                float v = yp[j] * zp[j];
                ushort_t hh, ll; splitf(v, hh, ll);
                ahi[mt][j] = (short)hh; alo[mt][j] = (short)ll;
            }
        }
        #pragma unroll
        for (int nt = 0; nt < 4; ++nt) {
            size_t wo = (size_t)(wn * 64 + nt * 16 + r16) * 128 + c * 32 + g * 8;
            bhi[nt] = *(const short8v*)(Wophi + wo);
            blo[nt] = *(const short8v*)(Woplo + wo);
        }
        #pragma unroll
        for (int mt = 0; mt < 4; ++mt)
            #pragma unroll
            for (int nt = 0; nt < 4; ++nt) {
                acc[mt][nt] = MFMA16(ahi[mt], bhi[nt], acc[mt][nt]);
                acc[mt][nt] = MFMA16(ahi[mt], blo[nt], acc[mt][nt]);
                acc[mt][nt] = MFMA16(alo[mt], bhi[nt], acc[mt][nt]);
            }
    }
    #pragma unroll
    for (int mt = 0; mt < 4; ++mt)
        #pragma unroll
        for (int nt = 0; nt < 4; ++nt)
            #pragma unroll
            for (int r = 0; r < 4; ++r) {
                int row = nbase + wm * 64 + mt * 16 + g * 4 + r;
                if (row < NN)
                    outp[(size_t)row * HD + wn * 64 + nt * 16 + r16] = acc[mt][nt][r];
            }
}

extern "C" void kernel_launch(void* const* d_in, const int* in_sizes, int n_in,
                              void* d_out, int out_size, void* d_ws, size_t ws_size,
                              hipStream_t stream)
{
    const float* h     = (const float*)d_in[0];
    const float* coord = (const float*)d_in[1];
    const int*   ei    = (const int*)d_in[2];
    const float* We1   = (const float*)d_in[3];
    const float* be1   = (const float*)d_in[4];
    const float* We2   = (const float*)d_in[5];
    const float* be2   = (const float*)d_in[6];
    const float* watt  = (const float*)d_in[7];
    const float* batt  = (const float*)d_in[8];
    const float* Wn1   = (const float*)d_in[9];
    const float* bn1   = (const float*)d_in[10];
    const float* Wn2   = (const float*)d_in[11];
    const float* bn2   = (const float*)d_in[12];
    const float* Wc1   = (const float*)d_in[13];
    const float* bc1   = (const float*)d_in[14];
    const float* Wc2   = (const float*)d_in[15];
    const float* lng   = (const float*)d_in[16];
    const float* lnb   = (const float*)d_in[17];
    const float* Wip   = (const float*)d_in[18];
    const float* convw = (const float*)d_in[19];
    const float* convb = (const float*)d_in[20];
    const float* Wxp   = (const float*)d_in[21];
    const float* Wdt   = (const float*)d_in[22];
    const float* bdt   = (const float*)d_in[23];
    const float* Alog  = (const float*)d_in[24];
    const float* Dskip = (const float*)d_in[25];
    const float* Wop   = (const float*)d_in[26];

    float* ws   = (float*)d_ws;
    float* mi   = ws;                                  // NN*HD f32 (zeroed; reused as y after node)
    float* ssum = mi   + (size_t)NN * HD;              // NN*3  f32 (zeroed)
    int*   histI  = (int*)(ssum + (size_t)NN * 3);     // NN (zeroed)
    int*   cursor = histI + NN;                        // NN (zeroed)
    int*   baseI  = cursor + NN;                       // NN
    int*   perm   = baseI + NN;                        // EE
    float* zsb  = (float*)(perm + EE);                 // NN*HD
    float* ucb  = zsb  + (size_t)NN * HD;              // NN*HD
    float* dtb  = ucb  + (size_t)NN * HD;              // NN*HD
    float* Bm   = dtb  + (size_t)NN * HD;              // NN*64
    float* Cm   = Bm   + (size_t)NN * 64;              // NN*64
    float* cP   = Cm   + (size_t)NN * 64;              // NC*8192
    float* cSb  = cP   + (size_t)NC * 8192;
    float* cIb  = cSb  + (size_t)NC * 8192;
    ushort_t* ub    = (ushort_t*)(cIb + (size_t)NC * 8192);  // NN*HD bf16
    ushort_t* W12bp = ub + (size_t)NN * HD;            // 256*128
    ushort_t* We2bp = W12bp + 256 * 128;
    ushort_t* Wc1bp = We2bp + 128 * 128;
    ushort_t* Wn1hi = Wc1bp + 128 * 128;               // 128*256 pair
    ushort_t* Wn1lo = Wn1hi + 128 * 256;
    ushort_t* Wn2hi = Wn1lo + 128 * 256;               // 128*128 pair
    ushort_t* Wn2lo = Wn2hi + 128 * 128;
    ushort_t* Wiphi = Wn2lo + 128 * 128;               // 256*128 pair
    ushort_t* Wiplo = Wiphi + 256 * 128;
    ushort_t* Wxp8hi = Wiplo + 256 * 128;              // 128*128 pairs
    ushort_t* Wxp8lo = Wxp8hi + 128 * 128;
    ushort_t* Wdt2hi = Wxp8lo + 128 * 128;
    ushort_t* Wdt2lo = Wdt2hi + 128 * 128;
    ushort_t* Wophi  = Wdt2lo + 128 * 128;
    ushort_t* Woplo  = Wophi + 128 * 128;
    // P12b (NN*256 bf16 = 10.24MB) aliases cP+cS: written by p12, dead after edge.
    ushort_t* P12bp = (ushort_t*)cP;
    // y aliases mi: mi consumed by node_mfma, re-zeroed each launch by the memset.
    float* yb = mi;

    float* outp     = (float*)d_out;
    float* coordout = outp + (size_t)NN * HD;

    // zero mi, ssum, histI, cursor
    hipMemsetAsync(ws, 0, (size_t)NN * 133 * 4, stream);

    prep_hist_kernel<<<(EE + 255) / 256, 256, 0, stream>>>(ei, histI,
                                         We1, We2, Wc1, Wn1, Wn2, Wip, Wxp, Wdt, Wop,
                                         W12bp, We2bp, Wc1bp,
                                         Wn1hi, Wn1lo, Wn2hi, Wn2lo, Wiphi, Wiplo,
                                         Wxp8hi, Wxp8lo, Wdt2hi, Wdt2lo, Wophi, Woplo);
    prefix_kernel<<<1, 1024, 0, stream>>>(histI, baseI);
    scatter_kernel<<<(EE + 255) / 256, 256, 0, stream>>>(ei, baseI, cursor, perm);
    p12_kernel<<<(NN + 127) / 128, 256, 0, stream>>>(h, W12bp, P12bp);
    edge_mfma<<<EE / 64, 256, 0, stream>>>(P12bp, coord, ei, perm, We1, be1,
                                           We2bp, be2, watt, batt, Wc1bp, bc1, Wc2,
                                           mi, ssum);
    node_mfma<<<(NN + 127) / 128, 256, 0, stream>>>(mi, h, Wn1hi, Wn1lo, bn1,
                                                    Wn2hi, Wn2lo, bn2, lng, lnb,
                                                    Wiphi, Wiplo, ub, zsb,
                                                    coord, ssum, histI, coordout);
    convdt_mfma<<<(NN + 127) / 128, 256, 0, stream>>>(ub, convw, convb,
                                                      Wxp8hi, Wxp8lo, Wdt2hi, Wdt2lo,
                                                      bdt, ucb, Bm, Cm, dtb);
    scan1_kernel<<<NC * 4096 / 256, 256, 0, stream>>>(dtb, ucb, Bm, Alog, cP, cSb);
    scan2_kernel<<<8192 / 256, 256, 0, stream>>>(cP, cSb, cIb);
    scan3_kernel<<<NC * 4096 / 256, 256, 0, stream>>>(dtb, ucb, Bm, Cm, Alog, Dskip, cIb, yb);
    out_mfma<<<(NN + 127) / 128, 256, 0, stream>>>(yb, zsb, Wophi, Woplo, outp);
}

// Round 16
// 640.105 us; speedup vs baseline: 1.0193x; 1.0193x over previous
//
#include <hip/hip_runtime.h>
#include <math.h>

#define NN 20000
#define EE 640000
#define HD 128
#define NC 160      // scan chunks
#define CS 125      // chunk size: NC*CS == NN

typedef unsigned short ushort_t;
typedef __attribute__((ext_vector_type(8))) short short8v;
typedef __attribute__((ext_vector_type(4))) float f32x4;

#define MFMA16(a,b,c) __builtin_amdgcn_mfma_f32_16x16x32_bf16(a,b,c,0,0,0)

__device__ __forceinline__ float sigf(float x) { return 1.0f / (1.0f + __expf(-x)); }

__device__ __forceinline__ ushort_t f2b(float x) {
    unsigned u = __builtin_bit_cast(unsigned, x);
    unsigned r = (u + 0x7FFFu + ((u >> 16) & 1u)) >> 16;
    return (ushort_t)r;
}
__device__ __forceinline__ float b2f(ushort_t u) {
    unsigned v = ((unsigned)u) << 16;
    return __builtin_bit_cast(float, v);
}
// split fp32 -> hi/lo bf16 pair (x ~= hi + lo, error ~2^-17 rel)
__device__ __forceinline__ void splitf(float v, ushort_t& h, ushort_t& l) {
    h = f2b(v);
    l = f2b(v - b2f(h));
}
__device__ __forceinline__ void cvt8x2(const float* p, short8v& hi, short8v& lo) {
    #pragma unroll
    for (int j = 0; j < 8; ++j) {
        float v = p[j];
        ushort_t h, l; splitf(v, h, l);
        hi[j] = (short)h; lo[j] = (short)l;
    }
}

// ---------------- prefix / scatter for counting sort ----------------
__global__ __launch_bounds__(1024) void prefix_kernel(const int* __restrict__ hist,
                                                      int* __restrict__ baseI)
{
    __shared__ int wsum[16];
    const int tid = threadIdx.x, lane = tid & 63, wid = tid >> 6;
    const int PER = 20;                 // 20*1024 >= NN
    int i0 = tid * PER;
    int s = 0;
    for (int k = 0; k < PER; ++k) { int i = i0 + k; if (i < NN) s += hist[i]; }
    int v = s;
    #pragma unroll
    for (int off = 1; off < 64; off <<= 1) {
        int t = __shfl_up(v, off);
        if (lane >= off) v += t;
    }
    if (lane == 63) wsum[wid] = v;
    __syncthreads();
    if (tid == 0) {
        int acc = 0;
        #pragma unroll
        for (int w = 0; w < 16; ++w) { int t = wsum[w]; wsum[w] = acc; acc += t; }
    }
    __syncthreads();
    int excl = v - s + wsum[wid];
    for (int k = 0; k < PER; ++k) {
        int i = i0 + k;
        if (i < NN) { baseI[i] = excl; excl += hist[i]; }
    }
}

__global__ __launch_bounds__(256) void scatter_kernel(const int* __restrict__ ei,
                                                      const int* __restrict__ baseI,
                                                      int* __restrict__ cursor,
                                                      int* __restrict__ perm)
{
    int i = blockIdx.x * 256 + threadIdx.x;
    if (i < EE) {
        int n = ei[i];
        int p = baseI[n] + atomicAdd(&cursor[n], 1);
        perm[p] = i;
    }
}

// ------- prep (weight conversions) + histogram, fused (independent work, one grid) -------
__global__ __launch_bounds__(256) void prep_hist_kernel(
    const int* __restrict__ ei, int* __restrict__ histI,
    const float* __restrict__ We1, const float* __restrict__ We2,
    const float* __restrict__ Wc1, const float* __restrict__ Wn1,
    const float* __restrict__ Wn2, const float* __restrict__ Wip,
    const float* __restrict__ Wxp, const float* __restrict__ Wdt,
    const float* __restrict__ Wop,
    ushort_t* __restrict__ W12b, ushort_t* __restrict__ We2b,
    ushort_t* __restrict__ Wc1b,
    ushort_t* __restrict__ Wn1hi, ushort_t* __restrict__ Wn1lo,
    ushort_t* __restrict__ Wn2hi, ushort_t* __restrict__ Wn2lo,
    ushort_t* __restrict__ Wiphi, ushort_t* __restrict__ Wiplo,
    ushort_t* __restrict__ Wxp8hi, ushort_t* __restrict__ Wxp8lo,
    ushort_t* __restrict__ Wdt2hi, ushort_t* __restrict__ Wdt2lo,
    ushort_t* __restrict__ Wophi, ushort_t* __restrict__ Woplo)
{
    int i = blockIdx.x * 256 + threadIdx.x;
    if (i < EE) atomicAdd(&histI[ei[i]], 1);
    if (i < 256 * 128) {
        int j = i >> 7, k = i & 127;
        W12b[i] = f2b(We1[(j & 127) * 257 + ((j >> 7) << 7) + k]);
        ushort_t h, l;
        splitf(Wn1[i], h, l); Wn1hi[i] = h; Wn1lo[i] = l;
        splitf(Wip[i], h, l); Wiphi[i] = h; Wiplo[i] = l;
    }
    if (i < 128 * 128) {
        We2b[i] = f2b(We2[i]);
        Wc1b[i] = f2b(Wc1[i]);
        ushort_t h, l;
        splitf(Wn2[i], h, l); Wn2hi[i] = h; Wn2lo[i] = l;
        splitf(Wop[i], h, l); Wophi[i] = h; Woplo[i] = l;
        int j = i >> 7, k = i & 127;
        splitf(Wxp[(8 + j) * 128 + k], h, l); Wxp8hi[i] = h; Wxp8lo[i] = l;
        float s = 0.f;
        #pragma unroll
        for (int r = 0; r < 8; ++r) s = fmaf(Wdt[j * 8 + r], Wxp[r * 128 + k], s);
        splitf(s, h, l); Wdt2hi[i] = h; Wdt2lo[i] = l;
    }
}

// ---------------- node projections: P12 = h @ [W1a|W1b]^T ----------------
__global__ __launch_bounds__(256) void p12_kernel(
    const float* __restrict__ h, const ushort_t* __restrict__ W12b,
    ushort_t* __restrict__ P12b)
{
    const int tid = threadIdx.x;
    const int lane = tid & 63;
    const int wid = tid >> 6;
    const int wm = wid >> 1, wn = wid & 1;
    const int g = lane >> 4, r16 = lane & 15;
    const int rbase = blockIdx.x * 128 + wm * 64;

    f32x4 acc[4][8];
    #pragma unroll
    for (int mt = 0; mt < 4; ++mt)
        #pragma unroll
        for (int nt = 0; nt < 8; ++nt) acc[mt][nt] = (f32x4){0.f, 0.f, 0.f, 0.f};

    for (int c = 0; c < 4; ++c) {
        short8v afr[4], bfr[8];
        #pragma unroll
        for (int mt = 0; mt < 4; ++mt) {
            int row = rbase + mt * 16 + r16;
            if (row > NN - 1) row = NN - 1;
            const float* p = h + (size_t)row * HD + c * 32 + g * 8;
            #pragma unroll
            for (int j = 0; j < 8; ++j) afr[mt][j] = (short)f2b(p[j]);
        }
        #pragma unroll
        for (int nt = 0; nt < 8; ++nt)
            bfr[nt] = *(const short8v*)(W12b + (size_t)(wn * 128 + nt * 16 + r16) * 128 + c * 32 + g * 8);
        #pragma unroll
        for (int mt = 0; mt < 4; ++mt)
            #pragma unroll
            for (int nt = 0; nt < 8; ++nt)
                acc[mt][nt] = MFMA16(afr[mt], bfr[nt], acc[mt][nt]);
    }
    #pragma unroll
    for (int mt = 0; mt < 4; ++mt)
        #pragma unroll
        for (int nt = 0; nt < 8; ++nt)
            #pragma unroll
            for (int r = 0; r < 4; ++r) {
                int row = rbase + mt * 16 + g * 4 + r;
                if (row < NN)
                    P12b[(size_t)row * 256 + wn * 128 + nt * 16 + r16] = f2b(acc[mt][nt][r]);
            }
}

// ---------------- edge phase (MFMA bf16, sorted edges, XCD-chunked swizzle) -------------
__global__ __launch_bounds__(256) void edge_mfma(
    const ushort_t* __restrict__ P12b, const float* __restrict__ coord,
    const int* __restrict__ ei, const int* __restrict__ perm,
    const float* __restrict__ We1, const float* __restrict__ be1,
    const ushort_t* __restrict__ We2b, const float* __restrict__ be2,
    const float* __restrict__ watt, const float* __restrict__ batt,
    const ushort_t* __restrict__ Wc1b, const float* __restrict__ bc1,
    const float* __restrict__ Wc2,
    float* __restrict__ mi, float* __restrict__ ssum)
{
    __shared__ ushort_t ybuf[128 * 128];
    __shared__ float cdp[128][3];
    __shared__ float wcols[128], be1s[128], be2s[128], bc1s[128], watts[128], wc2s[128];
    __shared__ float pq[2][128];
    __shared__ int ej0s[128];

    const int tid = threadIdx.x;
    // XCD-chunked bijective swizzle: 5000 blocks = 8 XCDs x 625 chunks.
    // Default assignment puts block b on XCD b%8; give each XCD a contiguous
    // e0-sorted range so P2 gathers + mi atomics stay XCD-L2-local.
    const int bid = blockIdx.x;
    const int ebase = ((bid & 7) * 625 + (bid >> 3)) * 128;
    const int lane = tid & 63;
    const int wid = tid >> 6;
    const int wm = wid >> 1, wn = wid & 1;
    const int g = lane >> 4, r16 = lane & 15;
    const float batt0 = batt[0];

    // ---- early: per-pair index load + RANDOM P1 gather, parked in own ybuf slots ----
    const int e = tid >> 1, hf = tid & 1;
    const int eg = perm[ebase + e];
    const int n0 = ei[eg];
    const int n1 = ei[EE + eg];
    {
        const ushort_t* p1 = P12b + (size_t)n1 * 256 + hf * 64;
        #pragma unroll
        for (int q = 0; q < 8; ++q) {
            short8v t = *(const short8v*)(p1 + q * 8);
            int off = (e << 8) + ((hf * 128 + q * 16) ^ ((e & 15) << 4));
            *(short8v*)((char*)ybuf + off) = t;     // thread-private slot
        }
    }
    if (hf == 0) ej0s[e] = n0;
    // stage per-col consts (latency overlaps gathers)
    {
        int t = tid & 127;
        if (tid < 128) {
            wcols[t] = We1[t * 257 + 256];
            be1s[t] = be1[t];
            be2s[t] = be2[t];
        } else {
            bc1s[t] = bc1[t];
            watts[t] = watt[t];
            wc2s[t] = Wc2[t];
        }
    }
    // radial + coord-diff (both pair threads compute rr; even thread writes cdp)
    float rr;
    {
        float d0 = coord[n0 * 3 + 0] - coord[n1 * 3 + 0];
        float d1 = coord[n0 * 3 + 1] - coord[n1 * 3 + 1];
        float d2 = coord[n0 * 3 + 2] - coord[n1 * 3 + 2];
        rr = d0 * d0 + d1 * d1 + d2 * d2;
        if (hf == 0) { cdp[e][0] = d0; cdp[e][1] = d1; cdp[e][2] = d2; }
    }
    __syncthreads();

    // ---- phase A: y1 = relu(P1[e1] + P2[e0] + rad*wcol + be1) -> ybuf (in place) ----
    {
        short8v gb[8];
        const ushort_t* p2 = P12b + (size_t)n0 * 256 + 128 + hf * 64;
        #pragma unroll
        for (int q = 0; q < 8; ++q)
            gb[q] = *(const short8v*)(p2 + q * 8);
        const int colbase = hf * 64;
        #pragma unroll
        for (int q = 0; q < 8; ++q) {
            int off = (e << 8) + ((colbase * 2 + q * 16) ^ ((e & 15) << 4));
            short8v a = *(const short8v*)((const char*)ybuf + off);
            short8v ov;
            #pragma unroll
            for (int jj = 0; jj < 8; ++jj) {
                int col = colbase + q * 8 + jj;
                float v = b2f((ushort_t)a[jj]) + b2f((ushort_t)gb[q][jj]) + rr * wcols[col] + be1s[col];
                ov[jj] = (short)f2b(fmaxf(v, 0.f));
            }
            *(short8v*)((char*)ybuf + off) = ov;
        }
    }
    // preload layer-2 weights (latency hides under the barrier)
    short8v b2_[4][4];
    {
        const ushort_t* W2p = We2b + (size_t)(wn * 64 + r16) * 128 + g * 8;
        #pragma unroll
        for (int nt = 0; nt < 4; ++nt)
            #pragma unroll
            for (int c = 0; c < 4; ++c)
                b2_[nt][c] = *(const short8v*)(W2p + nt * 2048 + c * 32);
    }
    __syncthreads();

    // ---- layer 2: y1 @ We2^T ----
    f32x4 acc[4][4];
    #pragma unroll
    for (int mt = 0; mt < 4; ++mt)
        #pragma unroll
        for (int nt = 0; nt < 4; ++nt) acc[mt][nt] = (f32x4){0.f, 0.f, 0.f, 0.f};
    #pragma unroll
    for (int c = 0; c < 4; ++c) {
        short8v afr[4];
        #pragma unroll
        for (int mt = 0; mt < 4; ++mt) {
            int row = wm * 64 + mt * 16 + r16;
            afr[mt] = *(const short8v*)((const char*)ybuf + (row << 8) + ((c * 64 + g * 16) ^ (r16 << 4)));
        }
        #pragma unroll
        for (int mt = 0; mt < 4; ++mt)
            #pragma unroll
            for (int nt = 0; nt < 4; ++nt)
                acc[mt][nt] = MFMA16(afr[mt], b2_[nt][c], acc[mt][nt]);
    }

    // epilogue 2: mij = relu(+be2); att = sigmoid(mij.watt + batt); ef = mij*att -> ybuf
    {
        float p[4][4];
        #pragma unroll
        for (int mt = 0; mt < 4; ++mt)
            #pragma unroll
            for (int r = 0; r < 4; ++r) p[mt][r] = 0.f;
        #pragma unroll
        for (int mt = 0; mt < 4; ++mt)
            #pragma unroll
            for (int nt = 0; nt < 4; ++nt)
                #pragma unroll
                for (int r = 0; r < 4; ++r) {
                    int col = wn * 64 + nt * 16 + r16;
                    float v = fmaxf(acc[mt][nt][r] + be2s[col], 0.f);
                    acc[mt][nt][r] = v;
                    p[mt][r] += v * watts[col];
                }
        #pragma unroll
        for (int off = 1; off < 16; off <<= 1)
            #pragma unroll
            for (int mt = 0; mt < 4; ++mt)
                #pragma unroll
                for (int r = 0; r < 4; ++r) p[mt][r] += __shfl_xor(p[mt][r], off);
        if (r16 == 0) {
            #pragma unroll
            for (int mt = 0; mt < 4; ++mt)
                #pragma unroll
                for (int r = 0; r < 4; ++r)
                    pq[wn][wm * 64 + mt * 16 + g * 4 + r] = p[mt][r];
        }
        __syncthreads();
        float att[4][4];
        #pragma unroll
        for (int mt = 0; mt < 4; ++mt)
            #pragma unroll
            for (int r = 0; r < 4; ++r) {
                int row = wm * 64 + mt * 16 + g * 4 + r;
                att[mt][r] = sigf(pq[0][row] + pq[1][row] + batt0);
            }
        __syncthreads();   // layer-2 ybuf reads + pq reads done -> safe to overwrite ybuf
        #pragma unroll
        for (int mt = 0; mt < 4; ++mt)
            #pragma unroll
            for (int nt = 0; nt < 4; ++nt)
                #pragma unroll
                for (int r = 0; r < 4; ++r) {
                    int row = wm * 64 + mt * 16 + g * 4 + r;
                    int col = wn * 64 + nt * 16 + r16;
                    int off = (row << 8) + (((col << 1)) ^ ((row & 15) << 4));
                    *(ushort_t*)((char*)ybuf + off) = f2b(acc[mt][nt][r] * att[mt][r]);
                }
    }
    __syncthreads();   // ef visible to all

    // preload layer-3 weights (latency hides under the segment-sum below)
    short8v b3_[4][4];
    {
        const ushort_t* W3p = Wc1b + (size_t)(wn * 64 + r16) * 128 + g * 8;
        #pragma unroll
        for (int nt = 0; nt < 4; ++nt)
            #pragma unroll
            for (int c = 0; c < 4; ++c)
                b3_[nt][c] = *(const short8v*)(W3p + nt * 2048 + c * 32);
    }

    // ---- segment-sum ef over sorted e0 runs -> mi ----
    // 256 threads = 64 col-pairs x 4 row-quarters; b32 LDS reads (2 cols at once);
    // flushes stay wave-coalesced (whole wave shares rows/cur, contiguous cols).
    {
        const int cp = tid & 63;          // cols 2*cp, 2*cp+1
        const int qr = tid >> 6;          // row quarter
        const int r0 = qr * 32, r1 = r0 + 32;
        const int colbyte = cp * 4;
        float s0 = 0.f, s1 = 0.f;
        int cur = ej0s[r0];
        for (int r = r0; r < r1; ++r) {
            int node = ej0s[r];
            if (node != cur) {
                atomicAdd(&mi[(size_t)cur * HD + 2 * cp], s0);
                atomicAdd(&mi[(size_t)cur * HD + 2 * cp + 1], s1);
                s0 = 0.f; s1 = 0.f; cur = node;
            }
            int off = (r << 8) + (colbyte ^ ((r & 15) << 4));
            unsigned v = *(const unsigned*)((const char*)ybuf + off);
            s0 += b2f((ushort_t)(v & 0xFFFFu));
            s1 += b2f((ushort_t)(v >> 16));
        }
        atomicAdd(&mi[(size_t)cur * HD + 2 * cp], s0);
        atomicAdd(&mi[(size_t)cur * HD + 2 * cp + 1], s1);
    }

    // ---- layer 3: ef @ Wc1^T, dot Wc2 ----
    #pragma unroll
    for (int mt = 0; mt < 4; ++mt)
        #pragma unroll
        for (int nt = 0; nt < 4; ++nt) acc[mt][nt] = (f32x4){0.f, 0.f, 0.f, 0.f};
    #pragma unroll
    for (int c = 0; c < 4; ++c) {
        short8v afr[4];
        #pragma unroll
        for (int mt = 0; mt < 4; ++mt) {
            int row = wm * 64 + mt * 16 + r16;
            afr[mt] = *(const short8v*)((const char*)ybuf + (row << 8) + ((c * 64 + g * 16) ^ (r16 << 4)));
        }
        #pragma unroll
        for (int mt = 0; mt < 4; ++mt)
            #pragma unroll
            for (int nt = 0; nt < 4; ++nt)
                acc[mt][nt] = MFMA16(afr[mt], b3_[nt][c], acc[mt][nt]);
    }
    {
        float q[4][4];
        #pragma unroll
        for (int mt = 0; mt < 4; ++mt)
            #pragma unroll
            for (int r = 0; r < 4; ++r) q[mt][r] = 0.f;
        #pragma unroll
        for (int mt = 0; mt < 4; ++mt)
            #pragma unroll
            for (int nt = 0; nt < 4; ++nt)
                #pragma unroll
                for (int r = 0; r < 4; ++r) {
                    int col = wn * 64 + nt * 16 + r16;
                    float v = fmaxf(acc[mt][nt][r] + bc1s[col], 0.f);
                    q[mt][r] += v * wc2s[col];
                }
        #pragma unroll
        for (int off = 1; off < 16; off <<= 1)
            #pragma unroll
            for (int mt = 0; mt < 4; ++mt)
                #pragma unroll
                for (int r = 0; r < 4; ++r) q[mt][r] += __shfl_xor(q[mt][r], off);
        if (r16 == 0) {
            #pragma unroll
            for (int mt = 0; mt < 4; ++mt)
                #pragma unroll
                for (int r = 0; r < 4; ++r)
                    pq[wn][wm * 64 + mt * 16 + g * 4 + r] = q[mt][r];
        }
        __syncthreads();
        // coord segment sums: 48 lanes, 8 rows each
        if (tid < 48) {
            int c = tid % 3, seg = tid / 3;
            int r0 = seg * 8, r1 = r0 + 8;
            float sacc = 0.f; int cur = ej0s[r0];
            for (int r = r0; r < r1; ++r) {
                int node = ej0s[r];
                if (node != cur) {
                    atomicAdd(&ssum[cur * 3 + c], sacc);
                    sacc = 0.f; cur = node;
                }
                float tv = pq[0][r] + pq[1][r];
                float tr = cdp[r][c] * tv;
                tr = fminf(fmaxf(tr, -100.f), 100.f);
                sacc += tr;
            }
            atomicAdd(&ssum[cur * 3 + c], sacc);
        }
    }
}

// -- node MLP + LN + clip (split MFMA); fused in_proj (u,z) + coord update; no hn roundtrip --
__global__ __launch_bounds__(256) void node_mfma(
    const float* __restrict__ mi, const float* __restrict__ h,
    const ushort_t* __restrict__ Wn1hi, const ushort_t* __restrict__ Wn1lo,
    const float* __restrict__ bn1,
    const ushort_t* __restrict__ Wn2hi, const ushort_t* __restrict__ Wn2lo,
    const float* __restrict__ bn2,
    const float* __restrict__ lng, const float* __restrict__ lnb,
    const ushort_t* __restrict__ Wiphi, const ushort_t* __restrict__ Wiplo,
    ushort_t* __restrict__ ub, float* __restrict__ zs,
    const float* __restrict__ coord, const float* __restrict__ ssum,
    const int* __restrict__ histI, float* __restrict__ coordout)
{
    __shared__ ushort_t yhi[128 * 128];
    __shared__ ushort_t ylo[128 * 128];
    __shared__ float bn1s[128], bn2s[128], lngs[128], lnbs[128];

    const int tid = threadIdx.x;
    const int nbase = blockIdx.x * 128;
    const int lane = tid & 63;
    const int wid = tid >> 6;
    const int wm = wid >> 1, wn = wid & 1;
    const int g = lane >> 4, r16 = lane & 15;

    if (tid < 128) { bn1s[tid] = bn1[tid]; bn2s[tid] = bn2[tid]; lngs[tid] = lng[tid]; lnbs[tid] = lnb[tid]; }
    __syncthreads();

    // layer 1: [mi | h] @ Wn1^T, K=256, split A and B
    f32x4 acc[4][4];
    #pragma unroll
    for (int mt = 0; mt < 4; ++mt)
        #pragma unroll
        for (int nt = 0; nt < 4; ++nt) acc[mt][nt] = (f32x4){0.f, 0.f, 0.f, 0.f};
    for (int c = 0; c < 8; ++c) {
        short8v ahi[4], alo[4], bhi[4], blo[4];
        #pragma unroll
        for (int mt = 0; mt < 4; ++mt) {
            int row = nbase + wm * 64 + mt * 16 + r16;
            if (row > NN - 1) row = NN - 1;
            const float* src = (c < 4) ? (mi + (size_t)row * HD + c * 32 + g * 8)
                                       : (h + (size_t)row * HD + (c - 4) * 32 + g * 8);
            cvt8x2(src, ahi[mt], alo[mt]);
        }
        #pragma unroll
        for (int nt = 0; nt < 4; ++nt) {
            size_t wo = (size_t)(wn * 64 + nt * 16 + r16) * 256 + c * 32 + g * 8;
            bhi[nt] = *(const short8v*)(Wn1hi + wo);
            blo[nt] = *(const short8v*)(Wn1lo + wo);
        }
        #pragma unroll
        for (int mt = 0; mt < 4; ++mt)
            #pragma unroll
            for (int nt = 0; nt < 4; ++nt) {
                acc[mt][nt] = MFMA16(ahi[mt], bhi[nt], acc[mt][nt]);
                acc[mt][nt] = MFMA16(ahi[mt], blo[nt], acc[mt][nt]);
                acc[mt][nt] = MFMA16(alo[mt], bhi[nt], acc[mt][nt]);
            }
    }
    // relu(+bn1) -> hi/lo LDS pair
    #pragma unroll
    for (int mt = 0; mt < 4; ++mt)
        #pragma unroll
        for (int nt = 0; nt < 4; ++nt)
            #pragma unroll
            for (int r = 0; r < 4; ++r) {
                int row = wm * 64 + mt * 16 + g * 4 + r;
                int col = wn * 64 + nt * 16 + r16;
                int off = (row << 8) + (((col << 1)) ^ ((row & 15) << 4));
                float v = fmaxf(acc[mt][nt][r] + bn1s[col], 0.f);
                ushort_t hh, ll; splitf(v, hh, ll);
                *(ushort_t*)((char*)yhi + off) = hh;
                *(ushort_t*)((char*)ylo + off) = ll;
            }
    __syncthreads();

    // layer 2: y1 @ Wn2^T, split A and B
    #pragma unroll
    for (int mt = 0; mt < 4; ++mt)
        #pragma unroll
        for (int nt = 0; nt < 4; ++nt) acc[mt][nt] = (f32x4){0.f, 0.f, 0.f, 0.f};
    #pragma unroll
    for (int c = 0; c < 4; ++c) {
        short8v ahi[4], alo[4], bhi[4], blo[4];
        #pragma unroll
        for (int mt = 0; mt < 4; ++mt) {
            int row = wm * 64 + mt * 16 + r16;
            int off = (row << 8) + ((c * 64 + g * 16) ^ (r16 << 4));
            ahi[mt] = *(const short8v*)((const char*)yhi + off);
            alo[mt] = *(const short8v*)((const char*)ylo + off);
        }
        #pragma unroll
        for (int nt = 0; nt < 4; ++nt) {
            size_t wo = (size_t)(wn * 64 + nt * 16 + r16) * 128 + c * 32 + g * 8;
            bhi[nt] = *(const short8v*)(Wn2hi + wo);
            blo[nt] = *(const short8v*)(Wn2lo + wo);
        }
        #pragma unroll
        for (int mt = 0; mt < 4; ++mt)
            #pragma unroll
            for (int nt = 0; nt < 4; ++nt) {
                acc[mt][nt] = MFMA16(ahi[mt], bhi[nt], acc[mt][nt]);
                acc[mt][nt] = MFMA16(ahi[mt], blo[nt], acc[mt][nt]);
                acc[mt][nt] = MFMA16(alo[mt], bhi[nt], acc[mt][nt]);
            }
    }
    __syncthreads();   // all layer-2 reads done -> safe to overwrite
    #pragma unroll
    for (int mt = 0; mt < 4; ++mt)
        #pragma unroll
        for (int nt = 0; nt < 4; ++nt)
            #pragma unroll
            for (int r = 0; r < 4; ++r) {
                int row = wm * 64 + mt * 16 + g * 4 + r;
                int col = wn * 64 + nt * 16 + r16;
                int off = (row << 8) + (((col << 1)) ^ ((row & 15) << 4));
                float v = acc[mt][nt][r] + bn2s[col];
                ushort_t hh, ll; splitf(v, hh, ll);
                *(ushort_t*)((char*)yhi + off) = hh;
                *(ushort_t*)((char*)ylo + off) = ll;
            }
    __syncthreads();

    // layernorm + clip; write hn (hi/lo split) back IN PLACE (thread-private slots)
    {
        const int row = tid >> 1, hf = tid & 1;
        float s1 = 0.f, s2 = 0.f;
        float vals[64];
        #pragma unroll
        for (int q = 0; q < 8; ++q) {
            int c8 = hf * 8 + q;
            int off = (row << 8) + ((c8 * 16) ^ ((row & 15) << 4));
            short8v vh = *(const short8v*)((const char*)yhi + off);
            short8v vl = *(const short8v*)((const char*)ylo + off);
            #pragma unroll
            for (int j = 0; j < 8; ++j) {
                float v = b2f((ushort_t)vh[j]) + b2f((ushort_t)vl[j]);
                vals[q * 8 + j] = v;
                s1 += v; s2 += v * v;
            }
        }
        s1 += __shfl_xor(s1, 1);
        s2 += __shfl_xor(s2, 1);
        float mu = s1 * (1.f / HD);
        float var = s2 * (1.f / HD) - mu * mu;
        float rs = rsqrtf(fmaxf(var, 0.f) + 1e-5f);
        #pragma unroll
        for (int q = 0; q < 8; ++q) {
            int c8 = hf * 8 + q;
            short8v oh, ol;
            #pragma unroll
            for (int j = 0; j < 8; ++j) {
                int col = c8 * 8 + j;
                float v = (vals[q * 8 + j] - mu) * rs * lngs[col] + lnbs[col];
                v = fminf(fmaxf(v, -10.f), 10.f);
                ushort_t hh, ll; splitf(v, hh, ll);
                oh[j] = (short)hh; ol[j] = (short)ll;
            }
            int off = (row << 8) + ((c8 * 16) ^ ((row & 15) << 4));
            *(short8v*)((char*)yhi + off) = oh;
            *(short8v*)((char*)ylo + off) = ol;
        }
    }

    // fused coord update (independent; overlaps with barrier)
    {
        int base3 = nbase * 3;
        for (int k = tid; k < 384; k += 256) {
            int idx = base3 + k;
            if (idx < NN * 3) {
                int n = idx / 3;
                coordout[idx] = coord[idx] + ssum[idx] / fmaxf((float)histI[n], 1.f);
            }
        }
    }
    __syncthreads();   // hn (hi/lo) visible to all

    // ---- fused in_proj: xz = hn @ Wip^T (256 cols, 2 passes of 64 cols per wave) ----
    #pragma unroll
    for (int jh = 0; jh < 2; ++jh) {
        #pragma unroll
        for (int mt = 0; mt < 4; ++mt)
            #pragma unroll
            for (int nt = 0; nt < 4; ++nt) acc[mt][nt] = (f32x4){0.f, 0.f, 0.f, 0.f};
        #pragma unroll
        for (int c = 0; c < 4; ++c) {
            short8v ahi[4], alo[4], bhi[4], blo[4];
            #pragma unroll
            for (int mt = 0; mt < 4; ++mt) {
                int row = wm * 64 + mt * 16 + r16;
                int off = (row << 8) + ((c * 64 + g * 16) ^ (r16 << 4));
                ahi[mt] = *(const short8v*)((const char*)yhi + off);
                alo[mt] = *(const short8v*)((const char*)ylo + off);
            }
            #pragma unroll
            for (int nt = 0; nt < 4; ++nt) {
                int j = wn * 128 + jh * 64 + nt * 16 + r16;
                size_t wo = (size_t)j * 128 + c * 32 + g * 8;
                bhi[nt] = *(const short8v*)(Wiphi + wo);
                blo[nt] = *(const short8v*)(Wiplo + wo);
            }
            #pragma unroll
            for (int mt = 0; mt < 4; ++mt)
                #pragma unroll
                for (int nt = 0; nt < 4; ++nt) {
                    acc[mt][nt] = MFMA16(ahi[mt], bhi[nt], acc[mt][nt]);
                    acc[mt][nt] = MFMA16(ahi[mt], blo[nt], acc[mt][nt]);
                    acc[mt][nt] = MFMA16(alo[mt], bhi[nt], acc[mt][nt]);
                }
        }
        #pragma unroll
        for (int mt = 0; mt < 4; ++mt)
            #pragma unroll
            for (int nt = 0; nt < 4; ++nt)
                #pragma unroll
                for (int r = 0; r < 4; ++r) {
                    int row = nbase + wm * 64 + mt * 16 + g * 4 + r;
                    if (row >= NN) continue;
                    int j = wn * 128 + jh * 64 + nt * 16 + r16;
                    float v = acc[mt][nt][r];
                    if (j < HD) ub[(size_t)row * HD + j] = f2b(v);
                    else        zs[(size_t)row * HD + (j - HD)] = v * sigf(v);
                }
    }
}

// ---- fused conv+silu -> uc; B|C = uc@Wxp8^T; dt = softplus(uc@Wdt2^T+bdt)  (split MFMA) ----
__global__ __launch_bounds__(256) void convdt_mfma(
    const ushort_t* __restrict__ ub, const float* __restrict__ cw,
    const float* __restrict__ cb,
    const ushort_t* __restrict__ Wxp8hi, const ushort_t* __restrict__ Wxp8lo,
    const ushort_t* __restrict__ Wdt2hi, const ushort_t* __restrict__ Wdt2lo,
    const float* __restrict__ bdt,
    float* __restrict__ uc, float* __restrict__ Bm, float* __restrict__ Cm,
    float* __restrict__ dt)
{
    __shared__ ushort_t yhi[128 * 128];
    __shared__ ushort_t ylo[128 * 128];
    __shared__ float cws[128][4], cbs[128], bdts[128];

    const int tid = threadIdx.x;
    const int nbase = blockIdx.x * 128;
    const int lane = tid & 63;
    const int wid = tid >> 6;
    const int wm = wid >> 1, wn = wid & 1;
    const int g = lane >> 4, r16 = lane & 15;

    if (tid < 128) {
        cbs[tid] = cb[tid]; bdts[tid] = bdt[tid];
        #pragma unroll
        for (int k = 0; k < 4; ++k) cws[tid][k] = cw[tid * 4 + k];
    }
    __syncthreads();

    // phase 1: causal depthwise conv + silu -> uc (fp32 global) + hi/lo LDS pair
    for (int it = tid; it < 128 * 16; it += 256) {
        int r = it >> 4, cg = it & 15;
        int t = nbase + r;
        int colb = cg * 8;
        float a[8];
        #pragma unroll
        for (int j = 0; j < 8; ++j) a[j] = cbs[colb + j];
        #pragma unroll
        for (int k = 0; k < 4; ++k) {
            int tt = t - 3 + k;
            if (tt >= 0 && tt < NN) {
                short8v uv = *(const short8v*)(ub + (size_t)tt * HD + colb);
                #pragma unroll
                for (int j = 0; j < 8; ++j) a[j] = fmaf(b2f((ushort_t)uv[j]), cws[colb + j][k], a[j]);
            }
        }
        short8v oh, ol;
        f32x4 u0, u1;
        #pragma unroll
        for (int j = 0; j < 8; ++j) {
            float s = (t < NN) ? a[j] * sigf(a[j]) : 0.f;
            ushort_t hh, ll; splitf(s, hh, ll);
            oh[j] = (short)hh; ol[j] = (short)ll;
            if (j < 4) u0[j] = s; else u1[j - 4] = s;
        }
        int off = (r << 8) + ((cg * 16) ^ ((r & 15) << 4));
        *(short8v*)((char*)yhi + off) = oh;
        *(short8v*)((char*)ylo + off) = ol;
        if (t < NN) {
            *(f32x4*)(uc + (size_t)t * HD + colb) = u0;
            *(f32x4*)(uc + (size_t)t * HD + colb + 4) = u1;
        }
    }
    __syncthreads();

    // phase 2: B|C = uc @ Wxp[8:136]^T  (128 cols), split
    f32x4 acc[4][4];
    #pragma unroll
    for (int mt = 0; mt < 4; ++mt)
        #pragma unroll
        for (int nt = 0; nt < 4; ++nt) acc[mt][nt] = (f32x4){0.f, 0.f, 0.f, 0.f};
    #pragma unroll
    for (int c = 0; c < 4; ++c) {
        short8v ahi[4], alo[4], bhi[4], blo[4];
        #pragma unroll
        for (int mt = 0; mt < 4; ++mt) {
            int row = wm * 64 + mt * 16 + r16;
            int off = (row << 8) + ((c * 64 + g * 16) ^ (r16 << 4));
            ahi[mt] = *(const short8v*)((const char*)yhi + off);
            alo[mt] = *(const short8v*)((const char*)ylo + off);
        }
        #pragma unroll
        for (int nt = 0; nt < 4; ++nt) {
            size_t wo = (size_t)(wn * 64 + nt * 16 + r16) * 128 + c * 32 + g * 8;
            bhi[nt] = *(const short8v*)(Wxp8hi + wo);
            blo[nt] = *(const short8v*)(Wxp8lo + wo);
        }
        #pragma unroll
        for (int mt = 0; mt < 4; ++mt)
            #pragma unroll
            for (int nt = 0; nt < 4; ++nt) {
                acc[mt][nt] = MFMA16(ahi[mt], bhi[nt], acc[mt][nt]);
                acc[mt][nt] = MFMA16(ahi[mt], blo[nt], acc[mt][nt]);
                acc[mt][nt] = MFMA16(alo[mt], bhi[nt], acc[mt][nt]);
            }
    }
    #pragma unroll
    for (int mt = 0; mt < 4; ++mt)
        #pragma unroll
        for (int nt = 0; nt < 4; ++nt)
            #pragma unroll
            for (int r = 0; r < 4; ++r) {
                int row = nbase + wm * 64 + mt * 16 + g * 4 + r;
                if (row >= NN) continue;
                int j = wn * 64 + nt * 16 + r16;
                float v = acc[mt][nt][r];
                if (j < 64) Bm[(size_t)row * 64 + j] = v;
                else        Cm[(size_t)row * 64 + (j - 64)] = v;
            }

    // phase 3: dt = softplus(uc @ Wdt2^T + bdt), split
    #pragma unroll
    for (int mt = 0; mt < 4; ++mt)
        #pragma unroll
        for (int nt = 0; nt < 4; ++nt) acc[mt][nt] = (f32x4){0.f, 0.f, 0.f, 0.f};
    #pragma unroll
    for (int c = 0; c < 4; ++c) {
        short8v ahi[4], alo[4], bhi[4], blo[4];
        #pragma unroll
        for (int mt = 0; mt < 4; ++mt) {
            int row = wm * 64 + mt * 16 + r16;
            int off = (row << 8) + ((c * 64 + g * 16) ^ (r16 << 4));
            ahi[mt] = *(const short8v*)((const char*)yhi + off);
            alo[mt] = *(const short8v*)((const char*)ylo + off);
        }
        #pragma unroll
        for (int nt = 0; nt < 4; ++nt) {
            size_t wo = (size_t)(wn * 64 + nt * 16 + r16) * 128 + c * 32 + g * 8;
            bhi[nt] = *(const short8v*)(Wdt2hi + wo);
            blo[nt] = *(const short8v*)(Wdt2lo + wo);
        }
        #pragma unroll
        for (int mt = 0; mt < 4; ++mt)
            #pragma unroll
            for (int nt = 0; nt < 4; ++nt) {
                acc[mt][nt] = MFMA16(ahi[mt], bhi[nt], acc[mt][nt]);
                acc[mt][nt] = MFMA16(ahi[mt], blo[nt], acc[mt][nt]);
                acc[mt][nt] = MFMA16(alo[mt], bhi[nt], acc[mt][nt]);
            }
    }
    #pragma unroll
    for (int mt = 0; mt < 4; ++mt)
        #pragma unroll
        for (int nt = 0; nt < 4; ++nt)
            #pragma unroll
            for (int r = 0; r < 4; ++r) {
                int row = nbase + wm * 64 + mt * 16 + g * 4 + r;
                if (row >= NN) continue;
                int j = wn * 64 + nt * 16 + r16;
                float a = acc[mt][nt][r] + bdts[j];
                float sp = (a > 20.f) ? a : log1pf(__expf(a));
                dt[(size_t)row * HD + j] = sp;
            }
}

// ---------------- chunked SSM scan (2 d-states per thread throughout) ----------------
__global__ __launch_bounds__(256) void scan1_kernel(
    const float* __restrict__ dt, const float* __restrict__ uc,
    const float* __restrict__ Bm, const float* __restrict__ Alog,
    float* __restrict__ cP, float* __restrict__ cS)
{
    int g = blockIdx.x * 256 + threadIdx.x;   // NC*4096 threads
    int c = g >> 12;
    int r = g & 4095;
    int hh = r >> 5;
    int dp = (r & 31) * 2;
    float A0 = -__expf(Alog[hh * 64 + dp]);
    float A1 = -__expf(Alog[hh * 64 + dp + 1]);
    float P0 = 1.f, S0 = 0.f, P1 = 1.f, S1 = 0.f;
    int t0 = c * CS;
    for (int t = t0; t < t0 + CS; ++t) {
        float dtv = dt[t * HD + hh];
        float uv = uc[t * HD + hh];
        float du = dtv * uv;
        float2 bv = *(const float2*)(Bm + (size_t)t * 64 + dp);
        float a0 = __expf(dtv * A0);
        float a1 = __expf(dtv * A1);
        P0 *= a0; P1 *= a1;
        S0 = fmaf(a0, S0, du * bv.x);
        S1 = fmaf(a1, S1, du * bv.y);
    }
    *(float2*)(cP + (size_t)c * 8192 + hh * 64 + dp) = make_float2(P0, P1);
    *(float2*)(cS + (size_t)c * 8192 + hh * 64 + dp) = make_float2(S0, S1);
}

__global__ __launch_bounds__(256) void scan2_kernel(
    const float* __restrict__ cP, const float* __restrict__ cS, float* __restrict__ cI)
{
    int g = blockIdx.x * 256 + threadIdx.x;
    float S = 0.f;
    for (int c = 0; c < NC; ++c) {
        cI[c * 8192 + g] = S;
        S = fmaf(cP[c * 8192 + g], S, cS[c * 8192 + g]);
    }
}

// 2 d-states per thread: 32 lanes per (c,hh); 5-level shfl reduce
__global__ __launch_bounds__(256) void scan3_kernel(
    const float* __restrict__ dt, const float* __restrict__ uc,
    const float* __restrict__ Bm, const float* __restrict__ Cm,
    const float* __restrict__ Alog, const float* __restrict__ Dskip,
    const float* __restrict__ cI, float* __restrict__ y)
{
    int g = blockIdx.x * 256 + threadIdx.x;   // NC*4096 threads
    int c = g >> 12;
    int r = g & 4095;
    int hh = r >> 5;
    int dp = (r & 31) * 2;
    float A0 = -__expf(Alog[hh * 64 + dp]);
    float A1 = -__expf(Alog[hh * 64 + dp + 1]);
    float s0 = cI[c * 8192 + hh * 64 + dp];
    float s1 = cI[c * 8192 + hh * 64 + dp + 1];
    float Dh = Dskip[hh];
    int t0 = c * CS;
    const int lane31 = threadIdx.x & 31;
    for (int t = t0; t < t0 + CS; ++t) {
        float dtv = dt[t * HD + hh];
        float uv = uc[t * HD + hh];
        float du = dtv * uv;
        float2 bv = *(const float2*)(Bm + (size_t)t * 64 + dp);
        float2 cv = *(const float2*)(Cm + (size_t)t * 64 + dp);
        s0 = fmaf(__expf(dtv * A0), s0, du * bv.x);
        s1 = fmaf(__expf(dtv * A1), s1, du * bv.y);
        float yp = fmaf(s0, cv.x, s1 * cv.y);
        #pragma unroll
        for (int off = 1; off < 32; off <<= 1) yp += __shfl_xor(yp, off);
        if (lane31 == 0) y[t * HD + hh] = yp + Dh * uv;
    }
}

// ---------------- out_proj (split MFMA, ~fp32): (y*silu(z)) @ Wop^T ----------------
__global__ __launch_bounds__(256) void out_mfma(
    const float* __restrict__ y, const float* __restrict__ zs,
    const ushort_t* __restrict__ Wophi, const ushort_t* __restrict__ Woplo,
    float* __restrict__ outp)
{
    const int tid = threadIdx.x;
    const int lane = tid & 63;
    const int wid = tid >> 6;
    const int wm = wid >> 1, wn = wid & 1;
    const int g = lane >> 4, r16 = lane & 15;
    const int nbase = blockIdx.x * 128;

    f32x4 acc[4][4];
    #pragma unroll
    for (int mt = 0; mt < 4; ++mt)
        #pragma unroll
        for (int nt = 0; nt < 4; ++nt) acc[mt][nt] = (f32x4){0.f, 0.f, 0.f, 0.f};

    for (int c = 0; c < 4; ++c) {
        short8v ahi[4], alo[4], bhi[4], blo[4];
        #pragma unroll
        for (int mt = 0; mt < 4; ++mt) {
            int row = nbase + wm * 64 + mt * 16 + r16;
            if (row > NN - 1) row = NN - 1;
            const float* yp = y + (size_t)row * HD + c * 32 + g * 8;
            const float* zp = zs + (size_t)row * HD + c * 32 + g * 8;
            #pragma unroll
            for (int j = 0; j < 8; ++j) {
                float v = yp[j] * zp[j];
                ushort_t hh, ll; splitf(v, hh, ll);
                ahi[mt][j] = (short)hh; alo[mt][j] = (short)ll;
            }
        }
        #pragma unroll
        for (int nt = 0; nt < 4; ++nt) {
            size_t wo = (size_t)(wn * 64 + nt * 16 + r16) * 128 + c * 32 + g * 8;
            bhi[nt] = *(const short8v*)(Wophi + wo);
            blo[nt] = *(const short8v*)(Woplo + wo);
        }
        #pragma unroll
        for (int mt = 0; mt < 4; ++mt)
            #pragma unroll
            for (int nt = 0; nt < 4; ++nt) {
                acc[mt][nt] = MFMA16(ahi[mt], bhi[nt], acc[mt][nt]);
                acc[mt][nt] = MFMA16(ahi[mt], blo[nt], acc[mt][nt]);
                acc[mt][nt] = MFMA16(alo[mt], bhi[nt], acc[mt][nt]);
            }
    }
    #pragma unroll
    for (int mt = 0; mt < 4; ++mt)
        #pragma unroll
        for (int nt = 0; nt < 4; ++nt)
            #pragma unroll
            for (int r = 0; r < 4; ++r) {
                int row = nbase + wm * 64 + mt * 16 + g * 4 + r;
                if (row < NN)
                    outp[(size_t)row * HD + wn * 64 + nt * 16 + r16] = acc[mt][nt][r];
            }
}

extern "C" void kernel_launch(void* const* d_in, const int* in_sizes, int n_in,
                              void* d_out, int out_size, void* d_ws, size_t ws_size,
                              hipStream_t stream)
{
    const float* h     = (const float*)d_in[0];
    const float* coord = (const float*)d_in[1];
    const int*   ei    = (const int*)d_in[2];
    const float* We1   = (const float*)d_in[3];
    const float* be1   = (const float*)d_in[4];
    const float* We2   = (const float*)d_in[5];
    const float* be2   = (const float*)d_in[6];
    const float* watt  = (const float*)d_in[7];
    const float* batt  = (const float*)d_in[8];
    const float* Wn1   = (const float*)d_in[9];
    const float* bn1   = (const float*)d_in[10];
    const float* Wn2   = (const float*)d_in[11];
    const float* bn2   = (const float*)d_in[12];
    const float* Wc1   = (const float*)d_in[13];
    const float* bc1   = (const float*)d_in[14];
    const float* Wc2   = (const float*)d_in[15];
    const float* lng   = (const float*)d_in[16];
    const float* lnb   = (const float*)d_in[17];
    const float* Wip   = (const float*)d_in[18];
    const float* convw = (const float*)d_in[19];
    const float* convb = (const float*)d_in[20];
    const float* Wxp   = (const float*)d_in[21];
    const float* Wdt   = (const float*)d_in[22];
    const float* bdt   = (const float*)d_in[23];
    const float* Alog  = (const float*)d_in[24];
    const float* Dskip = (const float*)d_in[25];
    const float* Wop   = (const float*)d_in[26];

    float* ws   = (float*)d_ws;
    float* mi   = ws;                                  // NN*HD f32 (zeroed; reused as y after node)
    float* ssum = mi   + (size_t)NN * HD;              // NN*3  f32 (zeroed)
    int*   histI  = (int*)(ssum + (size_t)NN * 3);     // NN (zeroed)
    int*   cursor = histI + NN;                        // NN (zeroed)
    int*   baseI  = cursor + NN;                       // NN
    int*   perm   = baseI + NN;                        // EE
    float* zsb  = (float*)(perm + EE);                 // NN*HD
    float* ucb  = zsb  + (size_t)NN * HD;              // NN*HD
    float* dtb  = ucb  + (size_t)NN * HD;              // NN*HD
    float* Bm   = dtb  + (size_t)NN * HD;              // NN*64
    float* Cm   = Bm   + (size_t)NN * 64;              // NN*64
    float* cP   = Cm   + (size_t)NN * 64;              // NC*8192
    float* cSb  = cP   + (size_t)NC * 8192;
    float* cIb  = cSb  + (size_t)NC * 8192;
    ushort_t* ub    = (ushort_t*)(cIb + (size_t)NC * 8192);  // NN*HD bf16
    ushort_t* W12bp = ub + (size_t)NN * HD;            // 256*128
    ushort_t* We2bp = W12bp + 256 * 128;
    ushort_t* Wc1bp = We2bp + 128 * 128;
    ushort_t* Wn1hi = Wc1bp + 128 * 128;               // 128*256 pair
    ushort_t* Wn1lo = Wn1hi + 128 * 256;
    ushort_t* Wn2hi = Wn1lo + 128 * 256;               // 128*128 pair
    ushort_t* Wn2lo = Wn2hi + 128 * 128;
    ushort_t* Wiphi = Wn2lo + 128 * 128;               // 256*128 pair
    ushort_t* Wiplo = Wiphi + 256 * 128;
    ushort_t* Wxp8hi = Wiplo + 256 * 128;              // 128*128 pairs
    ushort_t* Wxp8lo = Wxp8hi + 128 * 128;
    ushort_t* Wdt2hi = Wxp8lo + 128 * 128;
    ushort_t* Wdt2lo = Wdt2hi + 128 * 128;
    ushort_t* Wophi  = Wdt2lo + 128 * 128;
    ushort_t* Woplo  = Wophi + 128 * 128;
    // P12b (NN*256 bf16 = 10.24MB) aliases cP+cS: written by p12, dead after edge.
    ushort_t* P12bp = (ushort_t*)cP;
    // y aliases mi: mi consumed by node_mfma, re-zeroed each launch by the memset.
    float* yb = mi;

    float* outp     = (float*)d_out;
    float* coordout = outp + (size_t)NN * HD;

    // zero mi, ssum, histI, cursor
    hipMemsetAsync(ws, 0, (size_t)NN * 133 * 4, stream);

    prep_hist_kernel<<<(EE + 255) / 256, 256, 0, stream>>>(ei, histI,
                                         We1, We2, Wc1, Wn1, Wn2, Wip, Wxp, Wdt, Wop,
                                         W12bp, We2bp, Wc1bp,
                                         Wn1hi, Wn1lo, Wn2hi, Wn2lo, Wiphi, Wiplo,
                                         Wxp8hi, Wxp8lo, Wdt2hi, Wdt2lo, Wophi, Woplo);
    prefix_kernel<<<1, 1024, 0, stream>>>(histI, baseI);
    scatter_kernel<<<(EE + 255) / 256, 256, 0, stream>>>(ei, baseI, cursor, perm);
    p12_kernel<<<(NN + 127) / 128, 256, 0, stream>>>(h, W12bp, P12bp);
    edge_mfma<<<EE / 128, 256, 0, stream>>>(P12bp, coord, ei, perm, We1, be1,
                                            We2bp, be2, watt, batt, Wc1bp, bc1, Wc2,
                                            mi, ssum);
    node_mfma<<<(NN + 127) / 128, 256, 0, stream>>>(mi, h, Wn1hi, Wn1lo, bn1,
                                                    Wn2hi, Wn2lo, bn2, lng, lnb,
                                                    Wiphi, Wiplo, ub, zsb,
                                                    coord, ssum, histI, coordout);
    convdt_mfma<<<(NN + 127) / 128, 256, 0, stream>>>(ub, convw, convb,
                                                      Wxp8hi, Wxp8lo, Wdt2hi, Wdt2lo,
                                                      bdt, ucb, Bm, Cm, dtb);
    scan1_kernel<<<NC * 4096 / 256, 256, 0, stream>>>(dtb, ucb, Bm, Alog, cP, cSb);
    scan2_kernel<<<8192 / 256, 256, 0, stream>>>(cP, cSb, cIb);
    scan3_kernel<<<NC * 4096 / 256, 256, 0, stream>>>(dtb, ucb, Bm, Cm, Alog, Dskip, cIb, yb);
    out_mfma<<<(NN + 127) / 128, 256, 0, stream>>>(yb, zsb, Wophi, Woplo, outp);
}